// Round 5
// baseline (803.522 us; speedup 1.0000x reference)
//
#include <hip/hip_runtime.h>
#include <math.h>

#define NEG_ATT 0.2f
#define NEG 0.01f

typedef __attribute__((ext_vector_type(8))) short short8;
typedef __attribute__((ext_vector_type(4))) float f32x4;

static __device__ __forceinline__ float lrelu(float x, float s) { return x > 0.f ? x : s * x; }
static __device__ __forceinline__ unsigned short f2b(float f) {
  union { float f; unsigned int i; } v; v.f = f;
  unsigned int r = (v.i + 0x7fffu + ((v.i >> 16) & 1u)) >> 16;
  return (unsigned short)r;
}
static __device__ __forceinline__ void unpack8(uint4 r, float* x) {
  union { unsigned int u; float f; } t;
  t.u = r.x << 16;          x[0] = t.f;
  t.u = r.x & 0xffff0000u;  x[1] = t.f;
  t.u = r.y << 16;          x[2] = t.f;
  t.u = r.y & 0xffff0000u;  x[3] = t.f;
  t.u = r.z << 16;          x[4] = t.f;
  t.u = r.z & 0xffff0000u;  x[5] = t.f;
  t.u = r.w << 16;          x[6] = t.f;
  t.u = r.w & 0xffff0000u;  x[7] = t.f;
}
// async 16B/lane global->LDS copy; lds base must be wave-uniform, lane i lands at base+i*16
static __device__ __forceinline__ void async_copy16(const unsigned short* g, unsigned short* l) {
  __builtin_amdgcn_global_load_lds((const __attribute__((address_space(1))) unsigned int*)g,
                                   (__attribute__((address_space(3))) unsigned int*)l, 16, 0, 0);
}

// ---------------- CSR build ----------------
__global__ void zero_int_kernel(int* __restrict__ p, int n) {
  int i = blockIdx.x * blockDim.x + threadIdx.x;
  if (i < n) p[i] = 0;
}

__global__ void hist_kernel(const int* __restrict__ dst, int* __restrict__ cnt, int E, int N) {
  int i = blockIdx.x * blockDim.x + threadIdx.x;
  int tot = E + N;
  if (i >= tot) return;
  int d = (i < E) ? dst[i] : (i - E);
  atomicAdd(&cnt[d], 1);
}

// single-block exclusive scan, shfl-based
__global__ void scan_kernel(const int* __restrict__ cnt, int* __restrict__ rowptr,
                            int* __restrict__ cursor, int n) {
  __shared__ int wsum[16];
  __shared__ int carry_s;
  int t = threadIdx.x;           // 1024 threads
  int lane = t & 63, wv = t >> 6;
  if (t == 0) carry_s = 0;
  __syncthreads();
  for (int base = 0; base < n; base += 1024) {
    int i = base + t;
    int orig = (i < n) ? cnt[i] : 0;
    int v = orig;
    #pragma unroll
    for (int off = 1; off < 64; off <<= 1) {
      int u = __shfl_up(v, off);
      if (lane >= off) v += u;
    }
    if (lane == 63) wsum[wv] = v;
    __syncthreads();
    if (t < 16) {
      int s = wsum[t];
      #pragma unroll
      for (int off = 1; off < 16; off <<= 1) {
        int u = __shfl_up(s, off);
        if (t >= off) s += u;
      }
      wsum[t] = s;
    }
    __syncthreads();
    int waveoff = (wv > 0) ? wsum[wv - 1] : 0;
    int carry = carry_s;
    int excl = carry + waveoff + v - orig;
    if (i < n) { rowptr[i] = excl; cursor[i] = excl; }
    __syncthreads();
    if (t == 0) carry_s = carry + wsum[15];
    __syncthreads();
  }
  if (t == 0) rowptr[n] = carry_s;
}

__global__ void fill_kernel(const int* __restrict__ src, const int* __restrict__ dst,
                            int* __restrict__ cursor, int* __restrict__ colsrc, int E, int N) {
  int i = blockIdx.x * blockDim.x + threadIdx.x;
  int tot = E + N;
  if (i >= tot) return;
  int d, s;
  if (i < E) { d = dst[i]; s = src[i]; } else { d = i - E; s = i - E; }
  int pos = atomicAdd(&cursor[d], 1);
  colsrc[pos] = s;
}

// ---------------- weight transpose + bf16 convert: W[K][Ncol] f32 -> Wt[Ncol][K] bf16 ----
__global__ __launch_bounds__(256) void transpose_w_bf16(
    const float* __restrict__ W, unsigned short* __restrict__ Wt, int K, int Ncol) {
  __shared__ float t[32][33];
  int n0 = blockIdx.x * 32, k0 = blockIdx.y * 32;
  int tx = threadIdx.x & 31, ty = threadIdx.x >> 5;  // ty 0..7
  #pragma unroll
  for (int i = 0; i < 4; ++i)
    t[ty + i * 8][tx] = W[(size_t)(k0 + ty + i * 8) * Ncol + n0 + tx];
  __syncthreads();
  #pragma unroll
  for (int i = 0; i < 4; ++i)
    Wt[(size_t)(n0 + ty + i * 8) * K + k0 + tx] = f2b(t[tx][ty + i * 8]);
}

__global__ void f2b_kernel(const float* __restrict__ in, unsigned short* __restrict__ out, int n) {
  int i = blockIdx.x * blockDim.x + threadIdx.x;
  if (i < n) out[i] = f2b(in[i]);
}

// ---------------- bf16 MFMA GEMM, m97-style async staging ----------------
// A row-major [>=ceil(M/128)*128][K] bf16 (rows >= M may be garbage — C guarded).
// Bt row-major [Ncol][K] bf16 (Ncol = 128*gridDim.x).
// 128x128 tile, 256 thr = 4 waves (2x2 of 64x64), BK=32, mfma 16x16x32.
// LDS rows unpadded (64 B): fragment ds_read_b128 is 2-way bank aliased = free,
// and layout matches global_load_lds lane order exactly.
// Dual output: Cf (fp32, stride ldcf) if non-null; Cb (bf16, stride ldcb) if non-null.
__global__ __launch_bounds__(256) void gemm_mfma(
    const unsigned short* __restrict__ A, const unsigned short* __restrict__ Bt,
    const float* __restrict__ bias, float* __restrict__ Cf, unsigned short* __restrict__ Cb,
    int M, int K, int ldcf, int ldcb, int act) {
  __shared__ __align__(16) unsigned short As[128][32];
  __shared__ __align__(16) unsigned short Bs[128][32];
  int tid = threadIdx.x;
  int wave = tid >> 6, lane = tid & 63;
  int wm = wave >> 1, wn = wave & 1;
  int quad = lane >> 4, l16 = lane & 15;
  int row0 = blockIdx.y * 128, col0 = blockIdx.x * 128;
  int lrow = lane >> 2, lseg = lane & 3;    // staging: lane -> (row, 16B seg)

  // per-wave staging pointers: wave covers rows wave*32 .. wave*32+31 of each tile
  const unsigned short* gA = A + (size_t)(row0 + wave * 32 + lrow) * K + lseg * 8;
  const unsigned short* gB = Bt + (size_t)(col0 + wave * 32 + lrow) * K + lseg * 8;
  unsigned short* lA0 = &As[wave * 32][0];
  unsigned short* lA1 = &As[wave * 32 + 16][0];
  unsigned short* lB0 = &Bs[wave * 32][0];
  unsigned short* lB1 = &Bs[wave * 32 + 16][0];
  const size_t rstep = (size_t)16 * K;

  f32x4 acc[4][4];
  #pragma unroll
  for (int i = 0; i < 4; ++i)
    #pragma unroll
    for (int j = 0; j < 4; ++j)
      acc[i][j] = (f32x4){0.f, 0.f, 0.f, 0.f};

  for (int k0 = 0; k0 < K; k0 += 32) {
    async_copy16(gA + k0, lA0);
    async_copy16(gA + k0 + rstep, lA1);
    async_copy16(gB + k0, lB0);
    async_copy16(gB + k0 + rstep, lB1);
    __syncthreads();
    short8 afr[4], bfr[4];
    #pragma unroll
    for (int t = 0; t < 4; ++t) {
      afr[t] = *(const short8*)&As[wm * 64 + t * 16 + l16][quad * 8];
      bfr[t] = *(const short8*)&Bs[wn * 64 + t * 16 + l16][quad * 8];
    }
    #pragma unroll
    for (int mt = 0; mt < 4; ++mt)
      #pragma unroll
      for (int nt = 0; nt < 4; ++nt)
        acc[mt][nt] = __builtin_amdgcn_mfma_f32_16x16x32_bf16(afr[mt], bfr[nt], acc[mt][nt], 0, 0, 0);
    __syncthreads();
  }

  #pragma unroll
  for (int mt = 0; mt < 4; ++mt) {
    #pragma unroll
    for (int r = 0; r < 4; ++r) {
      int row = row0 + wm * 64 + mt * 16 + quad * 4 + r;
      if (row >= M) continue;
      #pragma unroll
      for (int nt = 0; nt < 4; ++nt) {
        int col = col0 + wn * 64 + nt * 16 + l16;
        float v = acc[mt][nt][r] + bias[col];
        if (act == 1) v = lrelu(v, NEG);
        if (Cf) Cf[(size_t)row * ldcf + col] = v;
        if (Cb) Cb[(size_t)row * ldcb + col] = f2b(v);
      }
    }
  }
}

// ---------------- GATv2 aggregation, 4 heads ----------------
// xlr: [n][2048] bf16, xl = cols 0..1023, xr = cols 1024..2047.
// block = node; wave = head; half-wave = one edge; lane = 8 channels.
__global__ __launch_bounds__(256) void gat_agg_h4(
    const unsigned short* __restrict__ xlr,
    const int* __restrict__ rowptr, const int* __restrict__ colsrc,
    const float* __restrict__ att, const float* __restrict__ bias,
    unsigned short* __restrict__ outb, int n) {
  const int S = 2048, XROFF = 1024;
  int d = blockIdx.x;
  if (d >= n) return;
  int hd = threadIdx.x >> 6, ln = threadIdx.x & 63;
  int half = ln >> 5, l32 = ln & 31;
  int c0 = l32 * 8;
  float a[8], a5[8], xr_[8];
  {
    float4 t0 = *(const float4*)(att + hd * 256 + c0);
    float4 t1 = *(const float4*)(att + hd * 256 + c0 + 4);
    a[0]=t0.x; a[1]=t0.y; a[2]=t0.z; a[3]=t0.w;
    a[4]=t1.x; a[5]=t1.y; a[6]=t1.z; a[7]=t1.w;
    #pragma unroll
    for (int c = 0; c < 8; ++c) a5[c] = NEG_ATT * a[c];
    uint4 r = *(const uint4*)(xlr + (size_t)d * S + XROFF + hd * 256 + c0);
    unpack8(r, xr_);
  }
  float m = -1e30f, l = 0.f, acc[8];
  #pragma unroll
  for (int c = 0; c < 8; ++c) acc[c] = 0.f;
  int beg = rowptr[d], end = rowptr[d + 1];
  for (int j = beg; j < end; j += 2) {
    int jj = j + half;
    bool valid = (jj < end);
    int s = colsrc[valid ? jj : j];
    uint4 raw = *(const uint4*)(xlr + (size_t)s * S + hd * 256 + c0);
    float x[8];
    unpack8(raw, x);
    float p = 0.f;
    #pragma unroll
    for (int c = 0; c < 8; ++c) {
      float u = x[c] + xr_[c];
      p = fmaf(u, (u > 0.f ? a[c] : a5[c]), p);
    }
    #pragma unroll
    for (int off = 16; off >= 1; off >>= 1) p += __shfl_xor(p, off);
    if (!valid) p = -1e30f;
    float nm = fmaxf(m, p);
    if (nm > m) {                   // new max: rescale old state
      float scl = __expf(m - nm);
      l *= scl;
      #pragma unroll
      for (int c = 0; c < 8; ++c) acc[c] *= scl;
      m = nm;
    }
    float w = __expf(p - m);
    l += w;
    #pragma unroll
    for (int c = 0; c < 8; ++c) acc[c] = fmaf(w, x[c], acc[c]);
  }
  // merge the two half-wave online-softmax states
  float mo = __shfl_xor(m, 32);
  float lo = __shfl_xor(l, 32);
  float M = fmaxf(m, mo);
  float sl = __expf(m - M);
  float so = __expf(mo - M);
  float L = fmaf(l, sl, lo * so);
  float inv = 1.f / L;
  float4 b0 = *(const float4*)(bias + hd * 256 + c0);
  float4 b1 = *(const float4*)(bias + hd * 256 + c0 + 4);
  float bb[8] = {b0.x, b0.y, b0.z, b0.w, b1.x, b1.y, b1.z, b1.w};
  unsigned int ou[4];
  #pragma unroll
  for (int c = 0; c < 8; ++c) {
    float po = __shfl_xor(acc[c], 32);
    float v = fmaf(acc[c], sl, po * so) * inv + bb[c];
    v = v > 0.f ? v : expm1f(v);     // ELU
    unsigned int bv = (unsigned int)f2b(v);
    if (c & 1) ou[c >> 1] |= bv << 16; else ou[c >> 1] = bv;
  }
  if (half == 0) {
    uint4 o = make_uint4(ou[0], ou[1], ou[2], ou[3]);
    *(uint4*)(outb + (size_t)d * 1024 + hd * 256 + c0) = o;
  }
}

// ---------------- GATv2 aggregation, 1 head, fp32 out, no activation ----------------
// xlr: [n][512] bf16, xl = cols 0..255, xr = cols 256..511.
// block = 4 waves = 4 nodes; half-wave = one edge; lane = 8 channels.
__global__ __launch_bounds__(256) void gat_agg_h1(
    const unsigned short* __restrict__ xlr,
    const int* __restrict__ rowptr, const int* __restrict__ colsrc,
    const float* __restrict__ att, const float* __restrict__ bias,
    float* __restrict__ out, int n) {
  const int S = 512, XROFF = 256;
  int wv = threadIdx.x >> 6, ln = threadIdx.x & 63;
  int d = blockIdx.x * 4 + wv;
  if (d >= n) return;
  int half = ln >> 5, l32 = ln & 31;
  int c0 = l32 * 8;
  float a[8], a5[8], xr_[8];
  {
    float4 t0 = *(const float4*)(att + c0);
    float4 t1 = *(const float4*)(att + c0 + 4);
    a[0]=t0.x; a[1]=t0.y; a[2]=t0.z; a[3]=t0.w;
    a[4]=t1.x; a[5]=t1.y; a[6]=t1.z; a[7]=t1.w;
    #pragma unroll
    for (int c = 0; c < 8; ++c) a5[c] = NEG_ATT * a[c];
    uint4 r = *(const uint4*)(xlr + (size_t)d * S + XROFF + c0);
    unpack8(r, xr_);
  }
  float m = -1e30f, l = 0.f, acc[8];
  #pragma unroll
  for (int c = 0; c < 8; ++c) acc[c] = 0.f;
  int beg = rowptr[d], end = rowptr[d + 1];
  for (int j = beg; j < end; j += 2) {
    int jj = j + half;
    bool valid = (jj < end);
    int s = colsrc[valid ? jj : j];
    uint4 raw = *(const uint4*)(xlr + (size_t)s * S + c0);
    float x[8];
    unpack8(raw, x);
    float p = 0.f;
    #pragma unroll
    for (int c = 0; c < 8; ++c) {
      float u = x[c] + xr_[c];
      p = fmaf(u, (u > 0.f ? a[c] : a5[c]), p);
    }
    #pragma unroll
    for (int off = 16; off >= 1; off >>= 1) p += __shfl_xor(p, off);
    if (!valid) p = -1e30f;
    float nm = fmaxf(m, p);
    if (nm > m) {
      float scl = __expf(m - nm);
      l *= scl;
      #pragma unroll
      for (int c = 0; c < 8; ++c) acc[c] *= scl;
      m = nm;
    }
    float w = __expf(p - m);
    l += w;
    #pragma unroll
    for (int c = 0; c < 8; ++c) acc[c] = fmaf(w, x[c], acc[c]);
  }
  float mo = __shfl_xor(m, 32);
  float lo = __shfl_xor(l, 32);
  float M = fmaxf(m, mo);
  float sl = __expf(m - M);
  float so = __expf(mo - M);
  float L = fmaf(l, sl, lo * so);
  float inv = 1.f / L;
  float4 b0 = *(const float4*)(bias + c0);
  float4 b1 = *(const float4*)(bias + c0 + 4);
  float bb[8] = {b0.x, b0.y, b0.z, b0.w, b1.x, b1.y, b1.z, b1.w};
  float ov[8];
  #pragma unroll
  for (int c = 0; c < 8; ++c) {
    float po = __shfl_xor(acc[c], 32);
    ov[c] = fmaf(acc[c], sl, po * so) * inv + bb[c];
  }
  if (half == 0) {
    float4 o0 = {ov[0], ov[1], ov[2], ov[3]};
    float4 o1 = {ov[4], ov[5], ov[6], ov[7]};
    *(float4*)(out + (size_t)d * 256 + c0) = o0;
    *(float4*)(out + (size_t)d * 256 + c0 + 4) = o1;
  }
}

// ---------------- final: logits = (leaky(h3,0.01)+h) @ W_out + b_out ----------------
__global__ __launch_bounds__(256) void final_logits(
    const float* __restrict__ h3, const float* __restrict__ h,
    const float* __restrict__ Wout, const float* __restrict__ bout,
    float* __restrict__ out, int n) {
  int wv = threadIdx.x >> 6, ln = threadIdx.x & 63;
  int node = blockIdx.x * 4 + wv;
  if (node >= n) return;
  int c0 = ln * 4;
  float4 a = *(const float4*)(h3 + (size_t)node * 256 + c0);
  float4 b = *(const float4*)(h + (size_t)node * 256 + c0);
  float4 w = *(const float4*)(Wout + c0);
  float vx = lrelu(a.x, NEG) + b.x;
  float vy = lrelu(a.y, NEG) + b.y;
  float vz = lrelu(a.z, NEG) + b.z;
  float vw = lrelu(a.w, NEG) + b.w;
  float v = vx * w.x + vy * w.y + vz * w.z + vw * w.w;
  #pragma unroll
  for (int off = 32; off >= 1; off >>= 1) v += __shfl_xor(v, off);
  if (ln == 0) out[node] = v + bout[0];
}

extern "C" void kernel_launch(void* const* d_in, const int* in_sizes, int n_in,
                              void* d_out, int out_size, void* d_ws, size_t ws_size,
                              hipStream_t stream) {
  const float* x    = (const float*)d_in[0];
  const int*   src  = (const int*)d_in[1];
  const int*   dst  = (const int*)d_in[2];
  const float* W_in = (const float*)d_in[3];
  const float* b_in = (const float*)d_in[4];
  const float* Wl1 = (const float*)d_in[5];  const float* bl1 = (const float*)d_in[6];
  const float* Wr1 = (const float*)d_in[7];  const float* br1 = (const float*)d_in[8];
  const float* att1 = (const float*)d_in[9]; const float* bias1 = (const float*)d_in[10];
  const float* Wl2 = (const float*)d_in[11]; const float* bl2 = (const float*)d_in[12];
  const float* Wr2 = (const float*)d_in[13]; const float* br2 = (const float*)d_in[14];
  const float* att2 = (const float*)d_in[15]; const float* bias2 = (const float*)d_in[16];
  const float* Wl3 = (const float*)d_in[17]; const float* bl3 = (const float*)d_in[18];
  const float* Wr3 = (const float*)d_in[19]; const float* br3 = (const float*)d_in[20];
  const float* att3 = (const float*)d_in[21]; const float* bias3 = (const float*)d_in[22];
  const float* W_out = (const float*)d_in[23]; const float* b_out = (const float*)d_in[24];

  const int N = in_sizes[0] / 64;
  const int E = in_sizes[1];
  const int NP = ((N + 127) / 128) * 128;   // padded rows for GEMM-A buffers
  float* out = (float*)d_out;

  // ---- workspace layout. Total ~226 MB ----
  char* p = (char*)d_ws;
  float* h   = (float*)p;            p += (size_t)N * 256 * 4;   // fp32 residual
  float* h3  = (float*)p;            p += (size_t)N * 256 * 4;   // fp32 layer3 out
  unsigned short* xbf  = (unsigned short*)p; p += (size_t)NP * 64 * 2;
  unsigned short* hbf  = (unsigned short*)p; p += (size_t)NP * 256 * 2;
  unsigned short* h1bf = (unsigned short*)p; p += (size_t)NP * 1024 * 2;
  unsigned short* h2bf = (unsigned short*)p; p += (size_t)NP * 1024 * 2;
  unsigned short* xlr  = (unsigned short*)p; p += (size_t)N * 2048 * 2;
  unsigned short* WtIn  = (unsigned short*)p; p += (size_t)256 * 64 * 2;
  unsigned short* WtLR1 = (unsigned short*)p; p += (size_t)2048 * 256 * 2;
  unsigned short* WtLR2 = (unsigned short*)p; p += (size_t)2048 * 1024 * 2;
  unsigned short* WtLR3 = (unsigned short*)p; p += (size_t)512 * 1024 * 2;
  float* bLR1 = (float*)p;           p += (size_t)2048 * 4;
  float* bLR2 = (float*)p;           p += (size_t)2048 * 4;
  float* bLR3 = (float*)p;           p += (size_t)512 * 4;
  int* cnt    = (int*)p;             p += (size_t)N * 4;
  int* cursor = (int*)p;             p += (size_t)N * 4;
  int* rowptr = (int*)p;             p += (size_t)(N + 1) * 4;
  int* colsrc = (int*)p;

  const int tot = E + N;
  dim3 blk(256);

  // CSR build (by dst, self loops appended)
  zero_int_kernel<<<(N + 255) / 256, blk, 0, stream>>>(cnt, N);
  hist_kernel<<<(tot + 255) / 256, blk, 0, stream>>>(dst, cnt, E, N);
  scan_kernel<<<1, 1024, 0, stream>>>(cnt, rowptr, cursor, N);
  fill_kernel<<<(tot + 255) / 256, blk, 0, stream>>>(src, dst, cursor, colsrc, E, N);

  // weight conversions: W[K][Ncol] -> Wt[Ncol][K] bf16, L/R fused along Ncol
  transpose_w_bf16<<<dim3(8, 2), blk, 0, stream>>>(W_in, WtIn, 64, 256);
  transpose_w_bf16<<<dim3(32, 8), blk, 0, stream>>>(Wl1, WtLR1, 256, 1024);
  transpose_w_bf16<<<dim3(32, 8), blk, 0, stream>>>(Wr1, WtLR1 + (size_t)1024 * 256, 256, 1024);
  transpose_w_bf16<<<dim3(32, 32), blk, 0, stream>>>(Wl2, WtLR2, 1024, 1024);
  transpose_w_bf16<<<dim3(32, 32), blk, 0, stream>>>(Wr2, WtLR2 + (size_t)1024 * 1024, 1024, 1024);
  transpose_w_bf16<<<dim3(8, 32), blk, 0, stream>>>(Wl3, WtLR3, 1024, 256);
  transpose_w_bf16<<<dim3(8, 32), blk, 0, stream>>>(Wr3, WtLR3 + (size_t)256 * 1024, 1024, 256);
  f2b_kernel<<<(N * 64 + 255) / 256, blk, 0, stream>>>(x, xbf, N * 64);

  // fused bias vectors
  hipMemcpyAsync(bLR1, bl1, 1024 * 4, hipMemcpyDeviceToDevice, stream);
  hipMemcpyAsync(bLR1 + 1024, br1, 1024 * 4, hipMemcpyDeviceToDevice, stream);
  hipMemcpyAsync(bLR2, bl2, 1024 * 4, hipMemcpyDeviceToDevice, stream);
  hipMemcpyAsync(bLR2 + 1024, br2, 1024 * 4, hipMemcpyDeviceToDevice, stream);
  hipMemcpyAsync(bLR3, bl3, 256 * 4, hipMemcpyDeviceToDevice, stream);
  hipMemcpyAsync(bLR3 + 256, br3, 256 * 4, hipMemcpyDeviceToDevice, stream);

  int gy = NP / 128;
  int gagg4 = N;
  int gagg1 = (N + 3) / 4;

  // h = leaky(x @ W_in + b_in): fp32 h + bf16 hbf
  gemm_mfma<<<dim3(2, gy), blk, 0, stream>>>(xbf, WtIn, b_in, h, hbf, N, 64, 256, 256, 1);

  // layer 1: K=256, fused L|R -> xlr [N,2048]
  gemm_mfma<<<dim3(16, gy), blk, 0, stream>>>(hbf, WtLR1, bLR1, nullptr, xlr, N, 256, 0, 2048, 0);
  gat_agg_h4<<<gagg4, blk, 0, stream>>>(xlr, rowptr, colsrc, att1, bias1, h1bf, N);

  // layer 2: K=1024, fused L|R -> xlr [N,2048]
  gemm_mfma<<<dim3(16, gy), blk, 0, stream>>>(h1bf, WtLR2, bLR2, nullptr, xlr, N, 1024, 0, 2048, 0);
  gat_agg_h4<<<gagg4, blk, 0, stream>>>(xlr, rowptr, colsrc, att2, bias2, h2bf, N);

  // layer 3: K=1024, fused L|R -> xlr [N,512]
  gemm_mfma<<<dim3(4, gy), blk, 0, stream>>>(h2bf, WtLR3, bLR3, nullptr, xlr, N, 1024, 0, 512, 0);
  gat_agg_h1<<<gagg1, blk, 0, stream>>>(xlr, rowptr, colsrc, att3, bias3, h3, N);

  // logits
  final_logits<<<gagg1, blk, 0, stream>>>(h3, h, W_out, b_out, out, N);
}

// Round 6
// 784.216 us; speedup vs baseline: 1.0246x; 1.0246x over previous
//
#include <hip/hip_runtime.h>
#include <math.h>

#define NEG_ATT 0.2f
#define NEG 0.01f

typedef __attribute__((ext_vector_type(8))) short short8;
typedef __attribute__((ext_vector_type(4))) float f32x4;

static __device__ __forceinline__ float lrelu(float x, float s) { return x > 0.f ? x : s * x; }
static __device__ __forceinline__ unsigned short f2b(float f) {
  union { float f; unsigned int i; } v; v.f = f;
  unsigned int r = (v.i + 0x7fffu + ((v.i >> 16) & 1u)) >> 16;
  return (unsigned short)r;
}
static __device__ __forceinline__ void unpack8(uint4 r, float* x) {
  union { unsigned int u; float f; } t;
  t.u = r.x << 16;          x[0] = t.f;
  t.u = r.x & 0xffff0000u;  x[1] = t.f;
  t.u = r.y << 16;          x[2] = t.f;
  t.u = r.y & 0xffff0000u;  x[3] = t.f;
  t.u = r.z << 16;          x[4] = t.f;
  t.u = r.z & 0xffff0000u;  x[5] = t.f;
  t.u = r.w << 16;          x[6] = t.f;
  t.u = r.w & 0xffff0000u;  x[7] = t.f;
}

// ---------------- CSR build ----------------
__global__ void zero_int_kernel(int* __restrict__ p, int n) {
  int i = blockIdx.x * blockDim.x + threadIdx.x;
  if (i < n) p[i] = 0;
}

__global__ void hist_kernel(const int* __restrict__ dst, int* __restrict__ cnt, int E, int N) {
  int i = blockIdx.x * blockDim.x + threadIdx.x;
  int tot = E + N;
  if (i >= tot) return;
  int d = (i < E) ? dst[i] : (i - E);
  atomicAdd(&cnt[d], 1);
}

// single-block exclusive scan, shfl-based
__global__ void scan_kernel(const int* __restrict__ cnt, int* __restrict__ rowptr,
                            int* __restrict__ cursor, int n) {
  __shared__ int wsum[16];
  __shared__ int carry_s;
  int t = threadIdx.x;           // 1024 threads
  int lane = t & 63, wv = t >> 6;
  if (t == 0) carry_s = 0;
  __syncthreads();
  for (int base = 0; base < n; base += 1024) {
    int i = base + t;
    int orig = (i < n) ? cnt[i] : 0;
    int v = orig;
    #pragma unroll
    for (int off = 1; off < 64; off <<= 1) {
      int u = __shfl_up(v, off);
      if (lane >= off) v += u;
    }
    if (lane == 63) wsum[wv] = v;
    __syncthreads();
    if (t < 16) {
      int s = wsum[t];
      #pragma unroll
      for (int off = 1; off < 16; off <<= 1) {
        int u = __shfl_up(s, off);
        if (t >= off) s += u;
      }
      wsum[t] = s;
    }
    __syncthreads();
    int waveoff = (wv > 0) ? wsum[wv - 1] : 0;
    int carry = carry_s;
    int excl = carry + waveoff + v - orig;
    if (i < n) { rowptr[i] = excl; cursor[i] = excl; }
    __syncthreads();
    if (t == 0) carry_s = carry + wsum[15];
    __syncthreads();
  }
  if (t == 0) rowptr[n] = carry_s;
}

__global__ void fill_kernel(const int* __restrict__ src, const int* __restrict__ dst,
                            int* __restrict__ cursor, int* __restrict__ colsrc, int E, int N) {
  int i = blockIdx.x * blockDim.x + threadIdx.x;
  int tot = E + N;
  if (i >= tot) return;
  int d, s;
  if (i < E) { d = dst[i]; s = src[i]; } else { d = i - E; s = i - E; }
  int pos = atomicAdd(&cursor[d], 1);
  colsrc[pos] = s;
}

// ---------------- weight transpose + bf16 convert: W[K][Ncol] f32 -> Wt[Ncol][K] bf16 ----
__global__ __launch_bounds__(256) void transpose_w_bf16(
    const float* __restrict__ W, unsigned short* __restrict__ Wt, int K, int Ncol) {
  __shared__ float t[32][33];
  int n0 = blockIdx.x * 32, k0 = blockIdx.y * 32;
  int tx = threadIdx.x & 31, ty = threadIdx.x >> 5;  // ty 0..7
  #pragma unroll
  for (int i = 0; i < 4; ++i)
    t[ty + i * 8][tx] = W[(size_t)(k0 + ty + i * 8) * Ncol + n0 + tx];
  __syncthreads();
  #pragma unroll
  for (int i = 0; i < 4; ++i)
    Wt[(size_t)(n0 + ty + i * 8) * K + k0 + tx] = f2b(t[tx][ty + i * 8]);
}

__global__ void f2b_kernel(const float* __restrict__ in, unsigned short* __restrict__ out, int n) {
  int i = blockIdx.x * blockDim.x + threadIdx.x;
  if (i < n) out[i] = f2b(in[i]);
}

// ---------------- bf16 MFMA GEMM: register-prefetch pipeline + XOR-swizzled LDS ----------
// A row-major [NP][K] bf16, NP = ceil(M/128)*128 (rows >= M garbage, C guarded).
// Bt row-major [Ncol][K] bf16 (Ncol = 128*gridDim.x).
// 128x128 tile, 256 thr = 4 waves (2x2 of 64x64), BK=32, mfma 16x16x32.
// LDS layout: row r (32 shorts) stored as 4 chunks of 8 shorts; chunk q lives at
// physical slot q ^ ((r>>1)&3). Makes both ds_write_b128 staging and ds_read_b128
// fragment reads conflict-free at the 8-lane phase level.
// Dual output: Cf (fp32, stride ldcf) if non-null; Cb (bf16, stride ldcb) if non-null.
__global__ __launch_bounds__(256) void gemm_mfma(
    const unsigned short* __restrict__ A, const unsigned short* __restrict__ Bt,
    const float* __restrict__ bias, float* __restrict__ Cf, unsigned short* __restrict__ Cb,
    int M, int K, int ldcf, int ldcb, int act) {
  __shared__ __align__(16) unsigned short As[128 * 32];
  __shared__ __align__(16) unsigned short Bs[128 * 32];
  int tid = threadIdx.x;
  int wave = tid >> 6, lane = tid & 63;
  int wm = wave >> 1, wn = wave & 1;
  int quad = lane >> 4, l16 = lane & 15;
  int row0 = blockIdx.y * 128, col0 = blockIdx.x * 128;
  int r0 = tid >> 2, seg0 = tid & 3;          // staging rows 0..63 (and +64)
  int swz0 = r0 * 32 + ((seg0 ^ ((r0 >> 1) & 3)) * 8);
  int swz1 = swz0 + 64 * 32;                  // row r0+64: same swizzle term
  int chunk = (quad ^ ((l16 >> 1) & 3)) * 8;  // frag-read swizzle, loop-invariant

  const unsigned short* gA = A + (size_t)(row0 + r0) * K + seg0 * 8;
  const unsigned short* gB = Bt + (size_t)(col0 + r0) * K + seg0 * 8;
  const size_t rstep = (size_t)64 * K;

  f32x4 acc[4][4];
  #pragma unroll
  for (int i = 0; i < 4; ++i)
    #pragma unroll
    for (int j = 0; j < 4; ++j)
      acc[i][j] = (f32x4){0.f, 0.f, 0.f, 0.f};

  uint4 sa0 = *(const uint4*)(gA);
  uint4 sa1 = *(const uint4*)(gA + rstep);
  uint4 sb0 = *(const uint4*)(gB);
  uint4 sb1 = *(const uint4*)(gB + rstep);

  for (int k0 = 0; k0 < K; k0 += 32) {
    *(uint4*)&As[swz0] = sa0;
    *(uint4*)&As[swz1] = sa1;
    *(uint4*)&Bs[swz0] = sb0;
    *(uint4*)&Bs[swz1] = sb1;
    __syncthreads();
    int kn = k0 + 32;
    if (kn < K) {     // prefetch next tile while MFMA block runs
      sa0 = *(const uint4*)(gA + kn);
      sa1 = *(const uint4*)(gA + kn + rstep);
      sb0 = *(const uint4*)(gB + kn);
      sb1 = *(const uint4*)(gB + kn + rstep);
    }
    short8 afr[4], bfr[4];
    #pragma unroll
    for (int t = 0; t < 4; ++t) {
      afr[t] = *(const short8*)&As[(wm * 64 + t * 16 + l16) * 32 + chunk];
      bfr[t] = *(const short8*)&Bs[(wn * 64 + t * 16 + l16) * 32 + chunk];
    }
    #pragma unroll
    for (int mt = 0; mt < 4; ++mt)
      #pragma unroll
      for (int nt = 0; nt < 4; ++nt)
        acc[mt][nt] = __builtin_amdgcn_mfma_f32_16x16x32_bf16(afr[mt], bfr[nt], acc[mt][nt], 0, 0, 0);
    __syncthreads();
  }

  #pragma unroll
  for (int mt = 0; mt < 4; ++mt) {
    #pragma unroll
    for (int r = 0; r < 4; ++r) {
      int row = row0 + wm * 64 + mt * 16 + quad * 4 + r;
      if (row >= M) continue;
      #pragma unroll
      for (int nt = 0; nt < 4; ++nt) {
        int col = col0 + wn * 64 + nt * 16 + l16;
        float v = acc[mt][nt][r] + bias[col];
        if (act == 1) v = lrelu(v, NEG);
        if (Cf) Cf[(size_t)row * ldcf + col] = v;
        if (Cb) Cb[(size_t)row * ldcb + col] = f2b(v);
      }
    }
  }
}

// ---------------- GATv2 aggregation, 4 heads ----------------
// xlr: [n][2048] bf16, xl = cols 0..1023, xr = cols 1024..2047.
// block = node; wave = head; half-wave = one edge; lane = 8 channels.
__global__ __launch_bounds__(256) void gat_agg_h4(
    const unsigned short* __restrict__ xlr,
    const int* __restrict__ rowptr, const int* __restrict__ colsrc,
    const float* __restrict__ att, const float* __restrict__ bias,
    unsigned short* __restrict__ outb, int n) {
  const int S = 2048, XROFF = 1024;
  int d = blockIdx.x;
  if (d >= n) return;
  int hd = threadIdx.x >> 6, ln = threadIdx.x & 63;
  int half = ln >> 5, l32 = ln & 31;
  int c0 = l32 * 8;
  float a[8], a5[8], xr_[8];
  {
    float4 t0 = *(const float4*)(att + hd * 256 + c0);
    float4 t1 = *(const float4*)(att + hd * 256 + c0 + 4);
    a[0]=t0.x; a[1]=t0.y; a[2]=t0.z; a[3]=t0.w;
    a[4]=t1.x; a[5]=t1.y; a[6]=t1.z; a[7]=t1.w;
    #pragma unroll
    for (int c = 0; c < 8; ++c) a5[c] = NEG_ATT * a[c];
    uint4 r = *(const uint4*)(xlr + (size_t)d * S + XROFF + hd * 256 + c0);
    unpack8(r, xr_);
  }
  float m = -1e30f, l = 0.f, acc[8];
  #pragma unroll
  for (int c = 0; c < 8; ++c) acc[c] = 0.f;
  int beg = rowptr[d], end = rowptr[d + 1];
  for (int j = beg; j < end; j += 2) {
    int jj = j + half;
    bool valid = (jj < end);
    int s = colsrc[valid ? jj : j];
    uint4 raw = *(const uint4*)(xlr + (size_t)s * S + hd * 256 + c0);
    float x[8];
    unpack8(raw, x);
    float p = 0.f;
    #pragma unroll
    for (int c = 0; c < 8; ++c) {
      float u = x[c] + xr_[c];
      p = fmaf(u, (u > 0.f ? a[c] : a5[c]), p);
    }
    #pragma unroll
    for (int off = 16; off >= 1; off >>= 1) p += __shfl_xor(p, off);
    if (!valid) p = -1e30f;
    float nm = fmaxf(m, p);
    if (nm > m) {                   // new max: rescale old state
      float scl = __expf(m - nm);
      l *= scl;
      #pragma unroll
      for (int c = 0; c < 8; ++c) acc[c] *= scl;
      m = nm;
    }
    float w = __expf(p - m);
    l += w;
    #pragma unroll
    for (int c = 0; c < 8; ++c) acc[c] = fmaf(w, x[c], acc[c]);
  }
  // merge the two half-wave online-softmax states
  float mo = __shfl_xor(m, 32);
  float lo = __shfl_xor(l, 32);
  float M = fmaxf(m, mo);
  float sl = __expf(m - M);
  float so = __expf(mo - M);
  float L = fmaf(l, sl, lo * so);
  float inv = 1.f / L;
  float4 b0 = *(const float4*)(bias + hd * 256 + c0);
  float4 b1 = *(const float4*)(bias + hd * 256 + c0 + 4);
  float bb[8] = {b0.x, b0.y, b0.z, b0.w, b1.x, b1.y, b1.z, b1.w};
  unsigned int ou[4];
  #pragma unroll
  for (int c = 0; c < 8; ++c) {
    float po = __shfl_xor(acc[c], 32);
    float v = fmaf(acc[c], sl, po * so) * inv + bb[c];
    v = v > 0.f ? v : expm1f(v);     // ELU
    unsigned int bv = (unsigned int)f2b(v);
    if (c & 1) ou[c >> 1] |= bv << 16; else ou[c >> 1] = bv;
  }
  if (half == 0) {
    uint4 o = make_uint4(ou[0], ou[1], ou[2], ou[3]);
    *(uint4*)(outb + (size_t)d * 1024 + hd * 256 + c0) = o;
  }
}

// ---------------- GATv2 aggregation, 1 head, fp32 out, no activation ----------------
// xlr: [n][512] bf16, xl = cols 0..255, xr = cols 256..511.
// block = 4 waves = 4 nodes; half-wave = one edge; lane = 8 channels.
__global__ __launch_bounds__(256) void gat_agg_h1(
    const unsigned short* __restrict__ xlr,
    const int* __restrict__ rowptr, const int* __restrict__ colsrc,
    const float* __restrict__ att, const float* __restrict__ bias,
    float* __restrict__ out, int n) {
  const int S = 512, XROFF = 256;
  int wv = threadIdx.x >> 6, ln = threadIdx.x & 63;
  int d = blockIdx.x * 4 + wv;
  if (d >= n) return;
  int half = ln >> 5, l32 = ln & 31;
  int c0 = l32 * 8;
  float a[8], a5[8], xr_[8];
  {
    float4 t0 = *(const float4*)(att + c0);
    float4 t1 = *(const float4*)(att + c0 + 4);
    a[0]=t0.x; a[1]=t0.y; a[2]=t0.z; a[3]=t0.w;
    a[4]=t1.x; a[5]=t1.y; a[6]=t1.z; a[7]=t1.w;
    #pragma unroll
    for (int c = 0; c < 8; ++c) a5[c] = NEG_ATT * a[c];
    uint4 r = *(const uint4*)(xlr + (size_t)d * S + XROFF + c0);
    unpack8(r, xr_);
  }
  float m = -1e30f, l = 0.f, acc[8];
  #pragma unroll
  for (int c = 0; c < 8; ++c) acc[c] = 0.f;
  int beg = rowptr[d], end = rowptr[d + 1];
  for (int j = beg; j < end; j += 2) {
    int jj = j + half;
    bool valid = (jj < end);
    int s = colsrc[valid ? jj : j];
    uint4 raw = *(const uint4*)(xlr + (size_t)s * S + c0);
    float x[8];
    unpack8(raw, x);
    float p = 0.f;
    #pragma unroll
    for (int c = 0; c < 8; ++c) {
      float u = x[c] + xr_[c];
      p = fmaf(u, (u > 0.f ? a[c] : a5[c]), p);
    }
    #pragma unroll
    for (int off = 16; off >= 1; off >>= 1) p += __shfl_xor(p, off);
    if (!valid) p = -1e30f;
    float nm = fmaxf(m, p);
    if (nm > m) {
      float scl = __expf(m - nm);
      l *= scl;
      #pragma unroll
      for (int c = 0; c < 8; ++c) acc[c] *= scl;
      m = nm;
    }
    float w = __expf(p - m);
    l += w;
    #pragma unroll
    for (int c = 0; c < 8; ++c) acc[c] = fmaf(w, x[c], acc[c]);
  }
  float mo = __shfl_xor(m, 32);
  float lo = __shfl_xor(l, 32);
  float M = fmaxf(m, mo);
  float sl = __expf(m - M);
  float so = __expf(mo - M);
  float L = fmaf(l, sl, lo * so);
  float inv = 1.f / L;
  float4 b0 = *(const float4*)(bias + c0);
  float4 b1 = *(const float4*)(bias + c0 + 4);
  float bb[8] = {b0.x, b0.y, b0.z, b0.w, b1.x, b1.y, b1.z, b1.w};
  float ov[8];
  #pragma unroll
  for (int c = 0; c < 8; ++c) {
    float po = __shfl_xor(acc[c], 32);
    ov[c] = fmaf(acc[c], sl, po * so) * inv + bb[c];
  }
  if (half == 0) {
    float4 o0 = {ov[0], ov[1], ov[2], ov[3]};
    float4 o1 = {ov[4], ov[5], ov[6], ov[7]};
    *(float4*)(out + (size_t)d * 256 + c0) = o0;
    *(float4*)(out + (size_t)d * 256 + c0 + 4) = o1;
  }
}

// ---------------- final: logits = (leaky(h3,0.01)+h) @ W_out + b_out ----------------
__global__ __launch_bounds__(256) void final_logits(
    const float* __restrict__ h3, const float* __restrict__ h,
    const float* __restrict__ Wout, const float* __restrict__ bout,
    float* __restrict__ out, int n) {
  int wv = threadIdx.x >> 6, ln = threadIdx.x & 63;
  int node = blockIdx.x * 4 + wv;
  if (node >= n) return;
  int c0 = ln * 4;
  float4 a = *(const float4*)(h3 + (size_t)node * 256 + c0);
  float4 b = *(const float4*)(h + (size_t)node * 256 + c0);
  float4 w = *(const float4*)(Wout + c0);
  float vx = lrelu(a.x, NEG) + b.x;
  float vy = lrelu(a.y, NEG) + b.y;
  float vz = lrelu(a.z, NEG) + b.z;
  float vw = lrelu(a.w, NEG) + b.w;
  float v = vx * w.x + vy * w.y + vz * w.z + vw * w.w;
  #pragma unroll
  for (int off = 32; off >= 1; off >>= 1) v += __shfl_xor(v, off);
  if (ln == 0) out[node] = v + bout[0];
}

extern "C" void kernel_launch(void* const* d_in, const int* in_sizes, int n_in,
                              void* d_out, int out_size, void* d_ws, size_t ws_size,
                              hipStream_t stream) {
  const float* x    = (const float*)d_in[0];
  const int*   src  = (const int*)d_in[1];
  const int*   dst  = (const int*)d_in[2];
  const float* W_in = (const float*)d_in[3];
  const float* b_in = (const float*)d_in[4];
  const float* Wl1 = (const float*)d_in[5];  const float* bl1 = (const float*)d_in[6];
  const float* Wr1 = (const float*)d_in[7];  const float* br1 = (const float*)d_in[8];
  const float* att1 = (const float*)d_in[9]; const float* bias1 = (const float*)d_in[10];
  const float* Wl2 = (const float*)d_in[11]; const float* bl2 = (const float*)d_in[12];
  const float* Wr2 = (const float*)d_in[13]; const float* br2 = (const float*)d_in[14];
  const float* att2 = (const float*)d_in[15]; const float* bias2 = (const float*)d_in[16];
  const float* Wl3 = (const float*)d_in[17]; const float* bl3 = (const float*)d_in[18];
  const float* Wr3 = (const float*)d_in[19]; const float* br3 = (const float*)d_in[20];
  const float* att3 = (const float*)d_in[21]; const float* bias3 = (const float*)d_in[22];
  const float* W_out = (const float*)d_in[23]; const float* b_out = (const float*)d_in[24];

  const int N = in_sizes[0] / 64;
  const int E = in_sizes[1];
  const int NP = ((N + 127) / 128) * 128;   // padded rows for GEMM-A buffers
  float* out = (float*)d_out;

  // ---- workspace layout. Total ~226 MB ----
  char* p = (char*)d_ws;
  float* h   = (float*)p;            p += (size_t)N * 256 * 4;   // fp32 residual
  float* h3  = (float*)p;            p += (size_t)N * 256 * 4;   // fp32 layer3 out
  unsigned short* xbf  = (unsigned short*)p; p += (size_t)NP * 64 * 2;
  unsigned short* hbf  = (unsigned short*)p; p += (size_t)NP * 256 * 2;
  unsigned short* h1bf = (unsigned short*)p; p += (size_t)NP * 1024 * 2;
  unsigned short* h2bf = (unsigned short*)p; p += (size_t)NP * 1024 * 2;
  unsigned short* xlr  = (unsigned short*)p; p += (size_t)N * 2048 * 2;
  unsigned short* WtIn  = (unsigned short*)p; p += (size_t)256 * 64 * 2;
  unsigned short* WtLR1 = (unsigned short*)p; p += (size_t)2048 * 256 * 2;
  unsigned short* WtLR2 = (unsigned short*)p; p += (size_t)2048 * 1024 * 2;
  unsigned short* WtLR3 = (unsigned short*)p; p += (size_t)512 * 1024 * 2;
  float* bLR1 = (float*)p;           p += (size_t)2048 * 4;
  float* bLR2 = (float*)p;           p += (size_t)2048 * 4;
  float* bLR3 = (float*)p;           p += (size_t)512 * 4;
  int* cnt    = (int*)p;             p += (size_t)N * 4;
  int* cursor = (int*)p;             p += (size_t)N * 4;
  int* rowptr = (int*)p;             p += (size_t)(N + 1) * 4;
  int* colsrc = (int*)p;

  const int tot = E + N;
  dim3 blk(256);

  // CSR build (by dst, self loops appended)
  zero_int_kernel<<<(N + 255) / 256, blk, 0, stream>>>(cnt, N);
  hist_kernel<<<(tot + 255) / 256, blk, 0, stream>>>(dst, cnt, E, N);
  scan_kernel<<<1, 1024, 0, stream>>>(cnt, rowptr, cursor, N);
  fill_kernel<<<(tot + 255) / 256, blk, 0, stream>>>(src, dst, cursor, colsrc, E, N);

  // weight conversions: W[K][Ncol] -> Wt[Ncol][K] bf16, L/R fused along Ncol
  transpose_w_bf16<<<dim3(8, 2), blk, 0, stream>>>(W_in, WtIn, 64, 256);
  transpose_w_bf16<<<dim3(32, 8), blk, 0, stream>>>(Wl1, WtLR1, 256, 1024);
  transpose_w_bf16<<<dim3(32, 8), blk, 0, stream>>>(Wr1, WtLR1 + (size_t)1024 * 256, 256, 1024);
  transpose_w_bf16<<<dim3(32, 32), blk, 0, stream>>>(Wl2, WtLR2, 1024, 1024);
  transpose_w_bf16<<<dim3(32, 32), blk, 0, stream>>>(Wr2, WtLR2 + (size_t)1024 * 1024, 1024, 1024);
  transpose_w_bf16<<<dim3(8, 32), blk, 0, stream>>>(Wl3, WtLR3, 1024, 256);
  transpose_w_bf16<<<dim3(8, 32), blk, 0, stream>>>(Wr3, WtLR3 + (size_t)256 * 1024, 1024, 256);
  f2b_kernel<<<(N * 64 + 255) / 256, blk, 0, stream>>>(x, xbf, N * 64);

  // fused bias vectors
  hipMemcpyAsync(bLR1, bl1, 1024 * 4, hipMemcpyDeviceToDevice, stream);
  hipMemcpyAsync(bLR1 + 1024, br1, 1024 * 4, hipMemcpyDeviceToDevice, stream);
  hipMemcpyAsync(bLR2, bl2, 1024 * 4, hipMemcpyDeviceToDevice, stream);
  hipMemcpyAsync(bLR2 + 1024, br2, 1024 * 4, hipMemcpyDeviceToDevice, stream);
  hipMemcpyAsync(bLR3, bl3, 256 * 4, hipMemcpyDeviceToDevice, stream);
  hipMemcpyAsync(bLR3 + 256, br3, 256 * 4, hipMemcpyDeviceToDevice, stream);

  int gy = NP / 128;
  int gagg4 = N;
  int gagg1 = (N + 3) / 4;

  // h = leaky(x @ W_in + b_in): fp32 h + bf16 hbf
  gemm_mfma<<<dim3(2, gy), blk, 0, stream>>>(xbf, WtIn, b_in, h, hbf, N, 64, 256, 256, 1);

  // layer 1: K=256, fused L|R -> xlr [N,2048]
  gemm_mfma<<<dim3(16, gy), blk, 0, stream>>>(hbf, WtLR1, bLR1, nullptr, xlr, N, 256, 0, 2048, 0);
  gat_agg_h4<<<gagg4, blk, 0, stream>>>(xlr, rowptr, colsrc, att1, bias1, h1bf, N);

  // layer 2: K=1024, fused L|R -> xlr [N,2048]
  gemm_mfma<<<dim3(16, gy), blk, 0, stream>>>(h1bf, WtLR2, bLR2, nullptr, xlr, N, 1024, 0, 2048, 0);
  gat_agg_h4<<<gagg4, blk, 0, stream>>>(xlr, rowptr, colsrc, att2, bias2, h2bf, N);

  // layer 3: K=1024, fused L|R -> xlr [N,512]
  gemm_mfma<<<dim3(4, gy), blk, 0, stream>>>(h2bf, WtLR3, bLR3, nullptr, xlr, N, 1024, 0, 512, 0);
  gat_agg_h1<<<gagg1, blk, 0, stream>>>(xlr, rowptr, colsrc, att3, bias3, h3, N);

  // logits
  final_logits<<<gagg1, blk, 0, stream>>>(h3, h, W_out, b_out, out, N);
}

// Round 7
// 741.902 us; speedup vs baseline: 1.0831x; 1.0570x over previous
//
#include <hip/hip_runtime.h>
#include <math.h>

#define NEG_ATT 0.2f
#define NEG 0.01f

typedef __attribute__((ext_vector_type(8))) short short8;
typedef __attribute__((ext_vector_type(4))) float f32x4;

static __device__ __forceinline__ float lrelu(float x, float s) { return x > 0.f ? x : s * x; }
static __device__ __forceinline__ unsigned short f2b(float f) {
  union { float f; unsigned int i; } v; v.f = f;
  unsigned int r = (v.i + 0x7fffu + ((v.i >> 16) & 1u)) >> 16;
  return (unsigned short)r;
}
static __device__ __forceinline__ void unpack8(uint4 r, float* x) {
  union { unsigned int u; float f; } t;
  t.u = r.x << 16;          x[0] = t.f;
  t.u = r.x & 0xffff0000u;  x[1] = t.f;
  t.u = r.y << 16;          x[2] = t.f;
  t.u = r.y & 0xffff0000u;  x[3] = t.f;
  t.u = r.z << 16;          x[4] = t.f;
  t.u = r.z & 0xffff0000u;  x[5] = t.f;
  t.u = r.w << 16;          x[6] = t.f;
  t.u = r.w & 0xffff0000u;  x[7] = t.f;
}

// ---------------- CSR build ----------------
__global__ void zero_int_kernel(int* __restrict__ p, int n) {
  int i = blockIdx.x * blockDim.x + threadIdx.x;
  if (i < n) p[i] = 0;
}

__global__ void hist_kernel(const int* __restrict__ dst, int* __restrict__ cnt, int E, int N) {
  int i = blockIdx.x * blockDim.x + threadIdx.x;
  int tot = E + N;
  if (i >= tot) return;
  int d = (i < E) ? dst[i] : (i - E);
  atomicAdd(&cnt[d], 1);
}

// single-block exclusive scan, shfl-based
__global__ void scan_kernel(const int* __restrict__ cnt, int* __restrict__ rowptr,
                            int* __restrict__ cursor, int n) {
  __shared__ int wsum[16];
  __shared__ int carry_s;
  int t = threadIdx.x;           // 1024 threads
  int lane = t & 63, wv = t >> 6;
  if (t == 0) carry_s = 0;
  __syncthreads();
  for (int base = 0; base < n; base += 1024) {
    int i = base + t;
    int orig = (i < n) ? cnt[i] : 0;
    int v = orig;
    #pragma unroll
    for (int off = 1; off < 64; off <<= 1) {
      int u = __shfl_up(v, off);
      if (lane >= off) v += u;
    }
    if (lane == 63) wsum[wv] = v;
    __syncthreads();
    if (t < 16) {
      int s = wsum[t];
      #pragma unroll
      for (int off = 1; off < 16; off <<= 1) {
        int u = __shfl_up(s, off);
        if (t >= off) s += u;
      }
      wsum[t] = s;
    }
    __syncthreads();
    int waveoff = (wv > 0) ? wsum[wv - 1] : 0;
    int carry = carry_s;
    int excl = carry + waveoff + v - orig;
    if (i < n) { rowptr[i] = excl; cursor[i] = excl; }
    __syncthreads();
    if (t == 0) carry_s = carry + wsum[15];
    __syncthreads();
  }
  if (t == 0) rowptr[n] = carry_s;
}

__global__ void fill_kernel(const int* __restrict__ src, const int* __restrict__ dst,
                            int* __restrict__ cursor, int* __restrict__ colsrc, int E, int N) {
  int i = blockIdx.x * blockDim.x + threadIdx.x;
  int tot = E + N;
  if (i >= tot) return;
  int d, s;
  if (i < E) { d = dst[i]; s = src[i]; } else { d = i - E; s = i - E; }
  int pos = atomicAdd(&cursor[d], 1);
  colsrc[pos] = s;
}

// ---------------- fused prep: 7 weight transposes + f2b(x) + bias concat ----------------
static __device__ __forceinline__ void do_transpose(
    const float* __restrict__ W, unsigned short* __restrict__ Wt,
    int K, int Ncol, int lbid, float (*t)[33]) {
  int nxb = Ncol >> 5;
  int bx = lbid % nxb, by = lbid / nxb;
  int n0 = bx * 32, k0 = by * 32;
  int tx = threadIdx.x & 31, ty = threadIdx.x >> 5;  // ty 0..7
  #pragma unroll
  for (int i = 0; i < 4; ++i)
    t[ty + i * 8][tx] = W[(size_t)(k0 + ty + i * 8) * Ncol + n0 + tx];
  __syncthreads();
  #pragma unroll
  for (int i = 0; i < 4; ++i)
    Wt[(size_t)(n0 + ty + i * 8) * K + k0 + tx] = f2b(t[tx][ty + i * 8]);
}

// block ranges: [0,16) t0 | [16,272) t1 | [272,528) t2 | [528,1552) t3 |
// [1552,2576) t4 | [2576,2832) t5 | [2832,3088) t6 | [3088,3106) bias | [3106,..) f2b(x)
__global__ __launch_bounds__(256) void prep_all(
    const float* __restrict__ W_in,
    const float* __restrict__ Wl1, const float* __restrict__ Wr1,
    const float* __restrict__ Wl2, const float* __restrict__ Wr2,
    const float* __restrict__ Wl3, const float* __restrict__ Wr3,
    unsigned short* __restrict__ WtIn,
    unsigned short* __restrict__ WtL1, unsigned short* __restrict__ WtR1,
    unsigned short* __restrict__ WtL2, unsigned short* __restrict__ WtR2,
    unsigned short* __restrict__ WtL3, unsigned short* __restrict__ WtR3,
    const float* __restrict__ x, unsigned short* __restrict__ xbf, int nx_elems,
    const float* __restrict__ bl1, const float* __restrict__ br1,
    const float* __restrict__ bl2, const float* __restrict__ br2,
    const float* __restrict__ bl3, const float* __restrict__ br3,
    float* __restrict__ bLR1, float* __restrict__ bLR2, float* __restrict__ bLR3) {
  __shared__ float t[32][33];
  int bid = blockIdx.x;
  if (bid < 16)        { do_transpose(W_in, WtIn, 64, 256, bid, t); return; }
  if (bid < 272)       { do_transpose(Wl1, WtL1, 256, 1024, bid - 16, t); return; }
  if (bid < 528)       { do_transpose(Wr1, WtR1, 256, 1024, bid - 272, t); return; }
  if (bid < 1552)      { do_transpose(Wl2, WtL2, 1024, 1024, bid - 528, t); return; }
  if (bid < 2576)      { do_transpose(Wr2, WtR2, 1024, 1024, bid - 1552, t); return; }
  if (bid < 2832)      { do_transpose(Wl3, WtL3, 1024, 256, bid - 2576, t); return; }
  if (bid < 3088)      { do_transpose(Wr3, WtR3, 1024, 256, bid - 2832, t); return; }
  if (bid < 3106) {
    int i = (bid - 3088) * 256 + threadIdx.x;   // 0..4607
    if (i < 1024)      bLR1[i] = bl1[i];
    else if (i < 2048) bLR1[i] = br1[i - 1024];
    else if (i < 3072) bLR2[i - 2048] = bl2[i - 2048];
    else if (i < 4096) bLR2[i - 2048] = br2[i - 3072];
    else if (i < 4352) bLR3[i - 4096] = bl3[i - 4096];
    else if (i < 4608) bLR3[i - 4096] = br3[i - 4352];
    return;
  }
  int i = (bid - 3106) * 256 + threadIdx.x;
  if (i < nx_elems) xbf[i] = f2b(x[i]);
}

// ---------------- bf16 MFMA GEMM: BK=64, register prefetch, XOR-swizzled LDS ----------
// A row-major [NP][K] bf16, NP = ceil(M/128)*128 (rows >= M garbage, C guarded).
// Bt row-major [Ncol][K] bf16 (Ncol = 128*gridDim.x). K multiple of 64.
// 128x128 tile, 256 thr = 4 waves (2x2 of 64x64), 2 sub-steps of mfma 16x16x32 per
// barrier pair (BK=64) -> half the barrier drains of BK=32.
// LDS row = 64 shorts (2 halves of 32); 16B chunk q of row r in half h lives at
// r*64 + h*32 + (q ^ ((r>>1)&3))*8  -> staging writes and frag reads both <=2-way.
__global__ __launch_bounds__(256) void gemm_mfma(
    const unsigned short* __restrict__ A, const unsigned short* __restrict__ Bt,
    const float* __restrict__ bias, float* __restrict__ Cf, unsigned short* __restrict__ Cb,
    int M, int K, int ldcf, int ldcb, int act) {
  __shared__ __align__(16) unsigned short As[128 * 64];
  __shared__ __align__(16) unsigned short Bs[128 * 64];
  int tid = threadIdx.x;
  int wave = tid >> 6, lane = tid & 63;
  int wm = wave >> 1, wn = wave & 1;
  int quad = lane >> 4, l16 = lane & 15;
  int row0 = blockIdx.y * 128, col0 = blockIdx.x * 128;
  int r0 = tid >> 2, seg0 = tid & 3;
  int swz = (seg0 ^ ((r0 >> 1) & 3)) * 8;
  int wsl0 = r0 * 64 + swz;            // row r0,    h=0
  int wsl1 = wsl0 + 32;                // row r0,    h=1
  int wsl2 = wsl0 + 64 * 64;           // row r0+64, h=0
  int wsl3 = wsl2 + 32;                // row r0+64, h=1
  int chunkbase = (quad ^ ((l16 >> 1) & 3)) * 8;

  const unsigned short* gA = A + (size_t)(row0 + r0) * K + seg0 * 8;
  const unsigned short* gB = Bt + (size_t)(col0 + r0) * K + seg0 * 8;
  const size_t rstep = (size_t)64 * K;

  f32x4 acc[4][4];
  #pragma unroll
  for (int i = 0; i < 4; ++i)
    #pragma unroll
    for (int j = 0; j < 4; ++j)
      acc[i][j] = (f32x4){0.f, 0.f, 0.f, 0.f};

  uint4 pa0 = *(const uint4*)(gA);
  uint4 pa1 = *(const uint4*)(gA + 32);
  uint4 pa2 = *(const uint4*)(gA + rstep);
  uint4 pa3 = *(const uint4*)(gA + rstep + 32);
  uint4 pb0 = *(const uint4*)(gB);
  uint4 pb1 = *(const uint4*)(gB + 32);
  uint4 pb2 = *(const uint4*)(gB + rstep);
  uint4 pb3 = *(const uint4*)(gB + rstep + 32);

  for (int k0 = 0; k0 < K; k0 += 64) {
    *(uint4*)&As[wsl0] = pa0;
    *(uint4*)&As[wsl1] = pa1;
    *(uint4*)&As[wsl2] = pa2;
    *(uint4*)&As[wsl3] = pa3;
    *(uint4*)&Bs[wsl0] = pb0;
    *(uint4*)&Bs[wsl1] = pb1;
    *(uint4*)&Bs[wsl2] = pb2;
    *(uint4*)&Bs[wsl3] = pb3;
    __syncthreads();
    int kn = k0 + 64;
    if (kn < K) {     // prefetch next slab while MFMA runs
      pa0 = *(const uint4*)(gA + kn);
      pa1 = *(const uint4*)(gA + kn + 32);
      pa2 = *(const uint4*)(gA + kn + rstep);
      pa3 = *(const uint4*)(gA + kn + rstep + 32);
      pb0 = *(const uint4*)(gB + kn);
      pb1 = *(const uint4*)(gB + kn + 32);
      pb2 = *(const uint4*)(gB + kn + rstep);
      pb3 = *(const uint4*)(gB + kn + rstep + 32);
    }
    #pragma unroll
    for (int h = 0; h < 2; ++h) {
      short8 afr[4], bfr[4];
      #pragma unroll
      for (int t = 0; t < 4; ++t) {
        afr[t] = *(const short8*)&As[(wm * 64 + t * 16 + l16) * 64 + h * 32 + chunkbase];
        bfr[t] = *(const short8*)&Bs[(wn * 64 + t * 16 + l16) * 64 + h * 32 + chunkbase];
      }
      #pragma unroll
      for (int mt = 0; mt < 4; ++mt)
        #pragma unroll
        for (int nt = 0; nt < 4; ++nt)
          acc[mt][nt] = __builtin_amdgcn_mfma_f32_16x16x32_bf16(afr[mt], bfr[nt], acc[mt][nt], 0, 0, 0);
    }
    __syncthreads();
  }

  #pragma unroll
  for (int mt = 0; mt < 4; ++mt) {
    #pragma unroll
    for (int r = 0; r < 4; ++r) {
      int row = row0 + wm * 64 + mt * 16 + quad * 4 + r;
      if (row >= M) continue;
      #pragma unroll
      for (int nt = 0; nt < 4; ++nt) {
        int col = col0 + wn * 64 + nt * 16 + l16;
        float v = acc[mt][nt][r] + bias[col];
        if (act == 1) v = lrelu(v, NEG);
        if (Cf) Cf[(size_t)row * ldcf + col] = v;
        if (Cb) Cb[(size_t)row * ldcb + col] = f2b(v);
      }
    }
  }
}

// ---------------- GATv2 aggregation, 4 heads ----------------
// xlr: [n][2048] bf16, xl = cols 0..1023, xr = cols 1024..2047.
// block = node; wave = head; half-wave = one edge; lane = 8 channels.
__global__ __launch_bounds__(256) void gat_agg_h4(
    const unsigned short* __restrict__ xlr,
    const int* __restrict__ rowptr, const int* __restrict__ colsrc,
    const float* __restrict__ att, const float* __restrict__ bias,
    unsigned short* __restrict__ outb, int n) {
  const int S = 2048, XROFF = 1024;
  int d = blockIdx.x;
  if (d >= n) return;
  int hd = threadIdx.x >> 6, ln = threadIdx.x & 63;
  int half = ln >> 5, l32 = ln & 31;
  int c0 = l32 * 8;
  float a[8], a5[8], xr_[8];
  {
    float4 t0 = *(const float4*)(att + hd * 256 + c0);
    float4 t1 = *(const float4*)(att + hd * 256 + c0 + 4);
    a[0]=t0.x; a[1]=t0.y; a[2]=t0.z; a[3]=t0.w;
    a[4]=t1.x; a[5]=t1.y; a[6]=t1.z; a[7]=t1.w;
    #pragma unroll
    for (int c = 0; c < 8; ++c) a5[c] = NEG_ATT * a[c];
    uint4 r = *(const uint4*)(xlr + (size_t)d * S + XROFF + hd * 256 + c0);
    unpack8(r, xr_);
  }
  float m = -1e30f, l = 0.f, acc[8];
  #pragma unroll
  for (int c = 0; c < 8; ++c) acc[c] = 0.f;
  int beg = rowptr[d], end = rowptr[d + 1];
  for (int j = beg; j < end; j += 2) {
    int jj = j + half;
    bool valid = (jj < end);
    int s = colsrc[valid ? jj : j];
    uint4 raw = *(const uint4*)(xlr + (size_t)s * S + hd * 256 + c0);
    float x[8];
    unpack8(raw, x);
    float p = 0.f;
    #pragma unroll
    for (int c = 0; c < 8; ++c) {
      float u = x[c] + xr_[c];
      p = fmaf(u, (u > 0.f ? a[c] : a5[c]), p);
    }
    #pragma unroll
    for (int off = 16; off >= 1; off >>= 1) p += __shfl_xor(p, off);
    if (!valid) p = -1e30f;
    float nm = fmaxf(m, p);
    if (nm > m) {                   // new max: rescale old state
      float scl = __expf(m - nm);
      l *= scl;
      #pragma unroll
      for (int c = 0; c < 8; ++c) acc[c] *= scl;
      m = nm;
    }
    float w = __expf(p - m);
    l += w;
    #pragma unroll
    for (int c = 0; c < 8; ++c) acc[c] = fmaf(w, x[c], acc[c]);
  }
  // merge the two half-wave online-softmax states
  float mo = __shfl_xor(m, 32);
  float lo = __shfl_xor(l, 32);
  float M = fmaxf(m, mo);
  float sl = __expf(m - M);
  float so = __expf(mo - M);
  float L = fmaf(l, sl, lo * so);
  float inv = 1.f / L;
  float4 b0 = *(const float4*)(bias + hd * 256 + c0);
  float4 b1 = *(const float4*)(bias + hd * 256 + c0 + 4);
  float bb[8] = {b0.x, b0.y, b0.z, b0.w, b1.x, b1.y, b1.z, b1.w};
  unsigned int ou[4];
  #pragma unroll
  for (int c = 0; c < 8; ++c) {
    float po = __shfl_xor(acc[c], 32);
    float v = fmaf(acc[c], sl, po * so) * inv + bb[c];
    v = v > 0.f ? v : expm1f(v);     // ELU
    unsigned int bv = (unsigned int)f2b(v);
    if (c & 1) ou[c >> 1] |= bv << 16; else ou[c >> 1] = bv;
  }
  if (half == 0) {
    uint4 o = make_uint4(ou[0], ou[1], ou[2], ou[3]);
    *(uint4*)(outb + (size_t)d * 1024 + hd * 256 + c0) = o;
  }
}

// ---------------- fused layer-3 agg + final logits ----------------
// xlr: [n][512] bf16, xl = 0..255, xr = 256..511. Computes h3 row (agg + bias3),
// then logits[d] = sum_c (leaky(h3_c,0.01)+h_c) * Wout_c + bout.
// block = 4 waves = 4 nodes; half-wave = one edge; lane = 8 channels.
__global__ __launch_bounds__(256) void gat_agg_h1_final(
    const unsigned short* __restrict__ xlr,
    const int* __restrict__ rowptr, const int* __restrict__ colsrc,
    const float* __restrict__ att, const float* __restrict__ bias,
    const float* __restrict__ h, const float* __restrict__ Wout,
    const float* __restrict__ bout, float* __restrict__ out, int n) {
  const int S = 512, XROFF = 256;
  int wv = threadIdx.x >> 6, ln = threadIdx.x & 63;
  int d = blockIdx.x * 4 + wv;
  if (d >= n) return;
  int half = ln >> 5, l32 = ln & 31;
  int c0 = l32 * 8;
  float a[8], a5[8], xr_[8];
  {
    float4 t0 = *(const float4*)(att + c0);
    float4 t1 = *(const float4*)(att + c0 + 4);
    a[0]=t0.x; a[1]=t0.y; a[2]=t0.z; a[3]=t0.w;
    a[4]=t1.x; a[5]=t1.y; a[6]=t1.z; a[7]=t1.w;
    #pragma unroll
    for (int c = 0; c < 8; ++c) a5[c] = NEG_ATT * a[c];
    uint4 r = *(const uint4*)(xlr + (size_t)d * S + XROFF + c0);
    unpack8(r, xr_);
  }
  float m = -1e30f, l = 0.f, acc[8];
  #pragma unroll
  for (int c = 0; c < 8; ++c) acc[c] = 0.f;
  int beg = rowptr[d], end = rowptr[d + 1];
  for (int j = beg; j < end; j += 2) {
    int jj = j + half;
    bool valid = (jj < end);
    int s = colsrc[valid ? jj : j];
    uint4 raw = *(const uint4*)(xlr + (size_t)s * S + c0);
    float x[8];
    unpack8(raw, x);
    float p = 0.f;
    #pragma unroll
    for (int c = 0; c < 8; ++c) {
      float u = x[c] + xr_[c];
      p = fmaf(u, (u > 0.f ? a[c] : a5[c]), p);
    }
    #pragma unroll
    for (int off = 16; off >= 1; off >>= 1) p += __shfl_xor(p, off);
    if (!valid) p = -1e30f;
    float nm = fmaxf(m, p);
    if (nm > m) {
      float scl = __expf(m - nm);
      l *= scl;
      #pragma unroll
      for (int c = 0; c < 8; ++c) acc[c] *= scl;
      m = nm;
    }
    float w = __expf(p - m);
    l += w;
    #pragma unroll
    for (int c = 0; c < 8; ++c) acc[c] = fmaf(w, x[c], acc[c]);
  }
  float mo = __shfl_xor(m, 32);
  float lo = __shfl_xor(l, 32);
  float M = fmaxf(m, mo);
  float sl = __expf(m - M);
  float so = __expf(mo - M);
  float L = fmaf(l, sl, lo * so);
  float inv = 1.f / L;
  float4 b0 = *(const float4*)(bias + c0);
  float4 b1 = *(const float4*)(bias + c0 + 4);
  float bb[8] = {b0.x, b0.y, b0.z, b0.w, b1.x, b1.y, b1.z, b1.w};
  float4 h0 = *(const float4*)(h + (size_t)d * 256 + c0);
  float4 h1v = *(const float4*)(h + (size_t)d * 256 + c0 + 4);
  float hh[8] = {h0.x, h0.y, h0.z, h0.w, h1v.x, h1v.y, h1v.z, h1v.w};
  float4 w0 = *(const float4*)(Wout + c0);
  float4 w1 = *(const float4*)(Wout + c0 + 4);
  float ww[8] = {w0.x, w0.y, w0.z, w0.w, w1.x, w1.y, w1.z, w1.w};
  float v = 0.f;
  #pragma unroll
  for (int c = 0; c < 8; ++c) {
    float h3c = fmaf(acc[c], sl, __shfl_xor(acc[c], 32) * so) * inv + bb[c];
    v = fmaf(lrelu(h3c, NEG) + hh[c], ww[c], v);
  }
  #pragma unroll
  for (int off = 16; off >= 1; off >>= 1) v += __shfl_xor(v, off);
  if (ln == 0) out[d] = v + bout[0];
}

extern "C" void kernel_launch(void* const* d_in, const int* in_sizes, int n_in,
                              void* d_out, int out_size, void* d_ws, size_t ws_size,
                              hipStream_t stream) {
  const float* x    = (const float*)d_in[0];
  const int*   src  = (const int*)d_in[1];
  const int*   dst  = (const int*)d_in[2];
  const float* W_in = (const float*)d_in[3];
  const float* b_in = (const float*)d_in[4];
  const float* Wl1 = (const float*)d_in[5];  const float* bl1 = (const float*)d_in[6];
  const float* Wr1 = (const float*)d_in[7];  const float* br1 = (const float*)d_in[8];
  const float* att1 = (const float*)d_in[9]; const float* bias1 = (const float*)d_in[10];
  const float* Wl2 = (const float*)d_in[11]; const float* bl2 = (const float*)d_in[12];
  const float* Wr2 = (const float*)d_in[13]; const float* br2 = (const float*)d_in[14];
  const float* att2 = (const float*)d_in[15]; const float* bias2 = (const float*)d_in[16];
  const float* Wl3 = (const float*)d_in[17]; const float* bl3 = (const float*)d_in[18];
  const float* Wr3 = (const float*)d_in[19]; const float* br3 = (const float*)d_in[20];
  const float* att3 = (const float*)d_in[21]; const float* bias3 = (const float*)d_in[22];
  const float* W_out = (const float*)d_in[23]; const float* b_out = (const float*)d_in[24];

  const int N = in_sizes[0] / 64;
  const int E = in_sizes[1];
  const int NP = ((N + 127) / 128) * 128;   // padded rows for GEMM-A buffers
  float* out = (float*)d_out;

  // ---- workspace layout. Total ~206 MB ----
  char* p = (char*)d_ws;
  float* h   = (float*)p;            p += (size_t)N * 256 * 4;   // fp32 residual
  unsigned short* xbf  = (unsigned short*)p; p += (size_t)NP * 64 * 2;
  unsigned short* hbf  = (unsigned short*)p; p += (size_t)NP * 256 * 2;
  unsigned short* h1bf = (unsigned short*)p; p += (size_t)NP * 1024 * 2;
  unsigned short* h2bf = (unsigned short*)p; p += (size_t)NP * 1024 * 2;
  unsigned short* xlr  = (unsigned short*)p; p += (size_t)N * 2048 * 2;
  unsigned short* WtIn  = (unsigned short*)p; p += (size_t)256 * 64 * 2;
  unsigned short* WtLR1 = (unsigned short*)p; p += (size_t)2048 * 256 * 2;
  unsigned short* WtLR2 = (unsigned short*)p; p += (size_t)2048 * 1024 * 2;
  unsigned short* WtLR3 = (unsigned short*)p; p += (size_t)512 * 1024 * 2;
  float* bLR1 = (float*)p;           p += (size_t)2048 * 4;
  float* bLR2 = (float*)p;           p += (size_t)2048 * 4;
  float* bLR3 = (float*)p;           p += (size_t)512 * 4;
  int* cnt    = (int*)p;             p += (size_t)N * 4;
  int* cursor = (int*)p;             p += (size_t)N * 4;
  int* rowptr = (int*)p;             p += (size_t)(N + 1) * 4;
  int* colsrc = (int*)p;

  const int tot = E + N;
  dim3 blk(256);

  // CSR build (by dst, self loops appended)
  zero_int_kernel<<<(N + 255) / 256, blk, 0, stream>>>(cnt, N);
  hist_kernel<<<(tot + 255) / 256, blk, 0, stream>>>(dst, cnt, E, N);
  scan_kernel<<<1, 1024, 0, stream>>>(cnt, rowptr, cursor, N);
  fill_kernel<<<(tot + 255) / 256, blk, 0, stream>>>(src, dst, cursor, colsrc, E, N);

  // fused prep: all transposes + f2b(x) + bias concat in one dispatch
  int nbf2b = (N * 64 + 255) / 256;
  prep_all<<<3106 + nbf2b, blk, 0, stream>>>(
      W_in, Wl1, Wr1, Wl2, Wr2, Wl3, Wr3,
      WtIn, WtLR1, WtLR1 + (size_t)1024 * 256,
      WtLR2, WtLR2 + (size_t)1024 * 1024,
      WtLR3, WtLR3 + (size_t)256 * 1024,
      x, xbf, N * 64,
      bl1, br1, bl2, br2, bl3, br3, bLR1, bLR2, bLR3);

  int gy = NP / 128;
  int gagg4 = N;
  int gagg1 = (N + 3) / 4;

  // h = leaky(x @ W_in + b_in): fp32 h + bf16 hbf   [K=64]
  gemm_mfma<<<dim3(2, gy), blk, 0, stream>>>(xbf, WtIn, b_in, h, hbf, N, 64, 256, 256, 1);

  // layer 1: K=256, fused L|R -> xlr [N,2048]
  gemm_mfma<<<dim3(16, gy), blk, 0, stream>>>(hbf, WtLR1, bLR1, nullptr, xlr, N, 256, 0, 2048, 0);
  gat_agg_h4<<<gagg4, blk, 0, stream>>>(xlr, rowptr, colsrc, att1, bias1, h1bf, N);

  // layer 2: K=1024, fused L|R -> xlr [N,2048]
  gemm_mfma<<<dim3(16, gy), blk, 0, stream>>>(h1bf, WtLR2, bLR2, nullptr, xlr, N, 1024, 0, 2048, 0);
  gat_agg_h4<<<gagg4, blk, 0, stream>>>(xlr, rowptr, colsrc, att2, bias2, h2bf, N);

  // layer 3: K=1024, fused L|R -> xlr [N,512]; agg + residual + logits fused
  gemm_mfma<<<dim3(4, gy), blk, 0, stream>>>(h2bf, WtLR3, bLR3, nullptr, xlr, N, 1024, 0, 512, 0);
  gat_agg_h1_final<<<gagg1, blk, 0, stream>>>(xlr, rowptr, colsrc, att3, bias3,
                                              h, W_out, b_out, out, N);
}

// Round 8
// 717.791 us; speedup vs baseline: 1.1194x; 1.0336x over previous
//
#include <hip/hip_runtime.h>
#include <math.h>

#define NEG_ATT 0.2f
#define NEG 0.01f

typedef __attribute__((ext_vector_type(8))) short short8;
typedef __attribute__((ext_vector_type(4))) float f32x4;

static __device__ __forceinline__ float lrelu(float x, float s) { return x > 0.f ? x : s * x; }
static __device__ __forceinline__ unsigned short f2b(float f) {
  union { float f; unsigned int i; } v; v.f = f;
  unsigned int r = (v.i + 0x7fffu + ((v.i >> 16) & 1u)) >> 16;
  return (unsigned short)r;
}
static __device__ __forceinline__ void unpack8(uint4 r, float* x) {
  union { unsigned int u; float f; } t;
  t.u = r.x << 16;          x[0] = t.f;
  t.u = r.x & 0xffff0000u;  x[1] = t.f;
  t.u = r.y << 16;          x[2] = t.f;
  t.u = r.y & 0xffff0000u;  x[3] = t.f;
  t.u = r.z << 16;          x[4] = t.f;
  t.u = r.z & 0xffff0000u;  x[5] = t.f;
  t.u = r.w << 16;          x[6] = t.f;
  t.u = r.w & 0xffff0000u;  x[7] = t.f;
}

// ---------------- CSR build ----------------
__global__ void zero_int_kernel(int* __restrict__ p, int n) {
  int i = blockIdx.x * blockDim.x + threadIdx.x;
  if (i < n) p[i] = 0;
}

__global__ void hist_kernel(const int* __restrict__ dst, int* __restrict__ cnt, int E, int N) {
  int i = blockIdx.x * blockDim.x + threadIdx.x;
  int tot = E + N;
  if (i >= tot) return;
  int d = (i < E) ? dst[i] : (i - E);
  atomicAdd(&cnt[d], 1);
}

// single-block exclusive scan, shfl-based
__global__ void scan_kernel(const int* __restrict__ cnt, int* __restrict__ rowptr,
                            int* __restrict__ cursor, int n) {
  __shared__ int wsum[16];
  __shared__ int carry_s;
  int t = threadIdx.x;           // 1024 threads
  int lane = t & 63, wv = t >> 6;
  if (t == 0) carry_s = 0;
  __syncthreads();
  for (int base = 0; base < n; base += 1024) {
    int i = base + t;
    int orig = (i < n) ? cnt[i] : 0;
    int v = orig;
    #pragma unroll
    for (int off = 1; off < 64; off <<= 1) {
      int u = __shfl_up(v, off);
      if (lane >= off) v += u;
    }
    if (lane == 63) wsum[wv] = v;
    __syncthreads();
    if (t < 16) {
      int s = wsum[t];
      #pragma unroll
      for (int off = 1; off < 16; off <<= 1) {
        int u = __shfl_up(s, off);
        if (t >= off) s += u;
      }
      wsum[t] = s;
    }
    __syncthreads();
    int waveoff = (wv > 0) ? wsum[wv - 1] : 0;
    int carry = carry_s;
    int excl = carry + waveoff + v - orig;
    if (i < n) { rowptr[i] = excl; cursor[i] = excl; }
    __syncthreads();
    if (t == 0) carry_s = carry + wsum[15];
    __syncthreads();
  }
  if (t == 0) rowptr[n] = carry_s;
}

__global__ void fill_kernel(const int* __restrict__ src, const int* __restrict__ dst,
                            int* __restrict__ cursor, int* __restrict__ colsrc, int E, int N) {
  int i = blockIdx.x * blockDim.x + threadIdx.x;
  int tot = E + N;
  if (i >= tot) return;
  int d, s;
  if (i < E) { d = dst[i]; s = src[i]; } else { d = i - E; s = i - E; }
  int pos = atomicAdd(&cursor[d], 1);
  colsrc[pos] = s;
}

// ---------------- fused prep: 7 weight transposes + f2b(x) + bias concat ----------------
static __device__ __forceinline__ void do_transpose(
    const float* __restrict__ W, unsigned short* __restrict__ Wt,
    int K, int Ncol, int lbid, float (*t)[33]) {
  int nxb = Ncol >> 5;
  int bx = lbid % nxb, by = lbid / nxb;
  int n0 = bx * 32, k0 = by * 32;
  int tx = threadIdx.x & 31, ty = threadIdx.x >> 5;  // ty 0..7
  #pragma unroll
  for (int i = 0; i < 4; ++i)
    t[ty + i * 8][tx] = W[(size_t)(k0 + ty + i * 8) * Ncol + n0 + tx];
  __syncthreads();
  #pragma unroll
  for (int i = 0; i < 4; ++i)
    Wt[(size_t)(n0 + ty + i * 8) * K + k0 + tx] = f2b(t[tx][ty + i * 8]);
}

// block ranges: [0,16) t0 | [16,272) t1 | [272,528) t2 | [528,1552) t3 |
// [1552,2576) t4 | [2576,2832) t5 | [2832,3088) t6 | [3088,3106) bias | [3106,..) f2b(x)
__global__ __launch_bounds__(256) void prep_all(
    const float* __restrict__ W_in,
    const float* __restrict__ Wl1, const float* __restrict__ Wr1,
    const float* __restrict__ Wl2, const float* __restrict__ Wr2,
    const float* __restrict__ Wl3, const float* __restrict__ Wr3,
    unsigned short* __restrict__ WtIn,
    unsigned short* __restrict__ WtL1, unsigned short* __restrict__ WtR1,
    unsigned short* __restrict__ WtL2, unsigned short* __restrict__ WtR2,
    unsigned short* __restrict__ WtL3, unsigned short* __restrict__ WtR3,
    const float* __restrict__ x, unsigned short* __restrict__ xbf, int nx_elems,
    const float* __restrict__ bl1, const float* __restrict__ br1,
    const float* __restrict__ bl2, const float* __restrict__ br2,
    const float* __restrict__ bl3, const float* __restrict__ br3,
    float* __restrict__ bLR1, float* __restrict__ bLR2, float* __restrict__ bLR3) {
  __shared__ float t[32][33];
  int bid = blockIdx.x;
  if (bid < 16)        { do_transpose(W_in, WtIn, 64, 256, bid, t); return; }
  if (bid < 272)       { do_transpose(Wl1, WtL1, 256, 1024, bid - 16, t); return; }
  if (bid < 528)       { do_transpose(Wr1, WtR1, 256, 1024, bid - 272, t); return; }
  if (bid < 1552)      { do_transpose(Wl2, WtL2, 1024, 1024, bid - 528, t); return; }
  if (bid < 2576)      { do_transpose(Wr2, WtR2, 1024, 1024, bid - 1552, t); return; }
  if (bid < 2832)      { do_transpose(Wl3, WtL3, 1024, 256, bid - 2576, t); return; }
  if (bid < 3088)      { do_transpose(Wr3, WtR3, 1024, 256, bid - 2832, t); return; }
  if (bid < 3106) {
    int i = (bid - 3088) * 256 + threadIdx.x;   // 0..4607
    if (i < 1024)      bLR1[i] = bl1[i];
    else if (i < 2048) bLR1[i] = br1[i - 1024];
    else if (i < 3072) bLR2[i - 2048] = bl2[i - 2048];
    else if (i < 4096) bLR2[i - 2048] = br2[i - 3072];
    else if (i < 4352) bLR3[i - 4096] = bl3[i - 4096];
    else if (i < 4608) bLR3[i - 4096] = br3[i - 4352];
    return;
  }
  int i = (bid - 3106) * 256 + threadIdx.x;
  if (i < nx_elems) xbf[i] = f2b(x[i]);
}

// ---------------- bf16 MFMA GEMM: BK=64, register prefetch, XOR-swizzled LDS ----------
__global__ __launch_bounds__(256) void gemm_mfma(
    const unsigned short* __restrict__ A, const unsigned short* __restrict__ Bt,
    const float* __restrict__ bias, float* __restrict__ Cf, unsigned short* __restrict__ Cb,
    int M, int K, int ldcf, int ldcb, int act) {
  __shared__ __align__(16) unsigned short As[128 * 64];
  __shared__ __align__(16) unsigned short Bs[128 * 64];
  int tid = threadIdx.x;
  int wave = tid >> 6, lane = tid & 63;
  int wm = wave >> 1, wn = wave & 1;
  int quad = lane >> 4, l16 = lane & 15;
  int row0 = blockIdx.y * 128, col0 = blockIdx.x * 128;
  int r0 = tid >> 2, seg0 = tid & 3;
  int swz = (seg0 ^ ((r0 >> 1) & 3)) * 8;
  int wsl0 = r0 * 64 + swz;            // row r0,    h=0
  int wsl1 = wsl0 + 32;                // row r0,    h=1
  int wsl2 = wsl0 + 64 * 64;           // row r0+64, h=0
  int wsl3 = wsl2 + 32;                // row r0+64, h=1
  int chunkbase = (quad ^ ((l16 >> 1) & 3)) * 8;

  const unsigned short* gA = A + (size_t)(row0 + r0) * K + seg0 * 8;
  const unsigned short* gB = Bt + (size_t)(col0 + r0) * K + seg0 * 8;
  const size_t rstep = (size_t)64 * K;

  f32x4 acc[4][4];
  #pragma unroll
  for (int i = 0; i < 4; ++i)
    #pragma unroll
    for (int j = 0; j < 4; ++j)
      acc[i][j] = (f32x4){0.f, 0.f, 0.f, 0.f};

  uint4 pa0 = *(const uint4*)(gA);
  uint4 pa1 = *(const uint4*)(gA + 32);
  uint4 pa2 = *(const uint4*)(gA + rstep);
  uint4 pa3 = *(const uint4*)(gA + rstep + 32);
  uint4 pb0 = *(const uint4*)(gB);
  uint4 pb1 = *(const uint4*)(gB + 32);
  uint4 pb2 = *(const uint4*)(gB + rstep);
  uint4 pb3 = *(const uint4*)(gB + rstep + 32);

  for (int k0 = 0; k0 < K; k0 += 64) {
    *(uint4*)&As[wsl0] = pa0;
    *(uint4*)&As[wsl1] = pa1;
    *(uint4*)&As[wsl2] = pa2;
    *(uint4*)&As[wsl3] = pa3;
    *(uint4*)&Bs[wsl0] = pb0;
    *(uint4*)&Bs[wsl1] = pb1;
    *(uint4*)&Bs[wsl2] = pb2;
    *(uint4*)&Bs[wsl3] = pb3;
    __syncthreads();
    int kn = k0 + 64;
    if (kn < K) {     // prefetch next slab while MFMA runs
      pa0 = *(const uint4*)(gA + kn);
      pa1 = *(const uint4*)(gA + kn + 32);
      pa2 = *(const uint4*)(gA + kn + rstep);
      pa3 = *(const uint4*)(gA + kn + rstep + 32);
      pb0 = *(const uint4*)(gB + kn);
      pb1 = *(const uint4*)(gB + kn + 32);
      pb2 = *(const uint4*)(gB + kn + rstep);
      pb3 = *(const uint4*)(gB + kn + rstep + 32);
    }
    #pragma unroll
    for (int h = 0; h < 2; ++h) {
      short8 afr[4], bfr[4];
      #pragma unroll
      for (int t = 0; t < 4; ++t) {
        afr[t] = *(const short8*)&As[(wm * 64 + t * 16 + l16) * 64 + h * 32 + chunkbase];
        bfr[t] = *(const short8*)&Bs[(wn * 64 + t * 16 + l16) * 64 + h * 32 + chunkbase];
      }
      #pragma unroll
      for (int mt = 0; mt < 4; ++mt)
        #pragma unroll
        for (int nt = 0; nt < 4; ++nt)
          acc[mt][nt] = __builtin_amdgcn_mfma_f32_16x16x32_bf16(afr[mt], bfr[nt], acc[mt][nt], 0, 0, 0);
    }
    __syncthreads();
  }

  #pragma unroll
  for (int mt = 0; mt < 4; ++mt) {
    #pragma unroll
    for (int r = 0; r < 4; ++r) {
      int row = row0 + wm * 64 + mt * 16 + quad * 4 + r;
      if (row >= M) continue;
      #pragma unroll
      for (int nt = 0; nt < 4; ++nt) {
        int col = col0 + wn * 64 + nt * 16 + l16;
        float v = acc[mt][nt][r] + bias[col];
        if (act == 1) v = lrelu(v, NEG);
        if (Cf) Cf[(size_t)row * ldcf + col] = v;
        if (Cb) Cb[(size_t)row * ldcb + col] = f2b(v);
      }
    }
  }
}

// ---------------- GATv2 aggregation, 4 heads: self-centered softmax, 4 edges/iter ----
// xlr: [n][2048] bf16, xl = cols 0..1023, xr = cols 1024..2047.
// block = node; wave = head; half-wave = one edge; lane = 8 channels.
// Softmax centered at the self-loop score (every node has one): no running max,
// no rescale, no divergent branch; halves share the center so merge is pure add.
__global__ __launch_bounds__(256) void gat_agg_h4(
    const unsigned short* __restrict__ xlr,
    const int* __restrict__ rowptr, const int* __restrict__ colsrc,
    const float* __restrict__ att, const float* __restrict__ bias,
    unsigned short* __restrict__ outb, int n) {
  const int S = 2048, XROFF = 1024;
  int d = blockIdx.x;
  if (d >= n) return;
  int hd = threadIdx.x >> 6, ln = threadIdx.x & 63;
  int half = ln >> 5, l32 = ln & 31;
  int c0 = l32 * 8;
  float a[8], xr_[8];
  {
    float4 t0 = *(const float4*)(att + hd * 256 + c0);
    float4 t1 = *(const float4*)(att + hd * 256 + c0 + 4);
    a[0]=t0.x; a[1]=t0.y; a[2]=t0.z; a[3]=t0.w;
    a[4]=t1.x; a[5]=t1.y; a[6]=t1.z; a[7]=t1.w;
    uint4 r = *(const uint4*)(xlr + (size_t)d * S + XROFF + hd * 256 + c0);
    unpack8(r, xr_);
  }
  // self-loop score as softmax center
  float ps = 0.f;
  {
    uint4 r = *(const uint4*)(xlr + (size_t)d * S + hd * 256 + c0);
    float xs[8];
    unpack8(r, xs);
    #pragma unroll
    for (int c = 0; c < 8; ++c) {
      float u = xs[c] + xr_[c];
      u = fmaxf(u, NEG_ATT * u);
      ps = fmaf(u, a[c], ps);
    }
    #pragma unroll
    for (int off = 16; off >= 1; off >>= 1) ps += __shfl_xor(ps, off);
  }
  float l = 0.f, acc[8];
  #pragma unroll
  for (int c = 0; c < 8; ++c) acc[c] = 0.f;
  int beg = rowptr[d], end = rowptr[d + 1];
  for (int j = beg; j < end; j += 4) {
    int j0 = j + half, j1 = j + 2 + half;
    bool v0 = j0 < end, v1 = j1 < end;
    int s0 = colsrc[v0 ? j0 : beg];
    int s1 = colsrc[v1 ? j1 : beg];
    uint4 r0 = *(const uint4*)(xlr + (size_t)s0 * S + hd * 256 + c0);
    uint4 r1 = *(const uint4*)(xlr + (size_t)s1 * S + hd * 256 + c0);
    float x0[8], x1[8];
    unpack8(r0, x0);
    unpack8(r1, x1);
    float p0 = 0.f, p1 = 0.f;
    #pragma unroll
    for (int c = 0; c < 8; ++c) {
      float u0 = x0[c] + xr_[c];
      float u1 = x1[c] + xr_[c];
      u0 = fmaxf(u0, NEG_ATT * u0);
      u1 = fmaxf(u1, NEG_ATT * u1);
      p0 = fmaf(u0, a[c], p0);
      p1 = fmaf(u1, a[c], p1);
    }
    #pragma unroll
    for (int off = 16; off >= 1; off >>= 1) {
      p0 += __shfl_xor(p0, off);
      p1 += __shfl_xor(p1, off);
    }
    float w0 = v0 ? __expf(p0 - ps) : 0.f;
    float w1 = v1 ? __expf(p1 - ps) : 0.f;
    l += w0 + w1;
    #pragma unroll
    for (int c = 0; c < 8; ++c) {
      acc[c] = fmaf(w0, x0[c], acc[c]);
      acc[c] = fmaf(w1, x1[c], acc[c]);
    }
  }
  // merge halves (shared center -> plain adds)
  l += __shfl_xor(l, 32);
  float inv = 1.f / l;
  float4 b0 = *(const float4*)(bias + hd * 256 + c0);
  float4 b1 = *(const float4*)(bias + hd * 256 + c0 + 4);
  float bb[8] = {b0.x, b0.y, b0.z, b0.w, b1.x, b1.y, b1.z, b1.w};
  unsigned int ou[4];
  #pragma unroll
  for (int c = 0; c < 8; ++c) {
    float s = acc[c] + __shfl_xor(acc[c], 32);
    float v = s * inv + bb[c];
    v = v > 0.f ? v : expm1f(v);     // ELU
    unsigned int bv = (unsigned int)f2b(v);
    if (c & 1) ou[c >> 1] |= bv << 16; else ou[c >> 1] = bv;
  }
  if (half == 0) {
    uint4 o = make_uint4(ou[0], ou[1], ou[2], ou[3]);
    *(uint4*)(outb + (size_t)d * 1024 + hd * 256 + c0) = o;
  }
}

// ---------------- fused layer-3 agg + final logits (self-centered, 4 edges/iter) ----
// xlr: [n][512] bf16, xl = 0..255, xr = 256..511.
// block = 4 waves = 4 nodes; half-wave = one edge; lane = 8 channels.
__global__ __launch_bounds__(256) void gat_agg_h1_final(
    const unsigned short* __restrict__ xlr,
    const int* __restrict__ rowptr, const int* __restrict__ colsrc,
    const float* __restrict__ att, const float* __restrict__ bias,
    const float* __restrict__ h, const float* __restrict__ Wout,
    const float* __restrict__ bout, float* __restrict__ out, int n) {
  const int S = 512, XROFF = 256;
  int wv = threadIdx.x >> 6, ln = threadIdx.x & 63;
  int d = blockIdx.x * 4 + wv;
  if (d >= n) return;
  int half = ln >> 5, l32 = ln & 31;
  int c0 = l32 * 8;
  float a[8], xr_[8];
  {
    float4 t0 = *(const float4*)(att + c0);
    float4 t1 = *(const float4*)(att + c0 + 4);
    a[0]=t0.x; a[1]=t0.y; a[2]=t0.z; a[3]=t0.w;
    a[4]=t1.x; a[5]=t1.y; a[6]=t1.z; a[7]=t1.w;
    uint4 r = *(const uint4*)(xlr + (size_t)d * S + XROFF + c0);
    unpack8(r, xr_);
  }
  float ps = 0.f;
  {
    uint4 r = *(const uint4*)(xlr + (size_t)d * S + c0);
    float xs[8];
    unpack8(r, xs);
    #pragma unroll
    for (int c = 0; c < 8; ++c) {
      float u = xs[c] + xr_[c];
      u = fmaxf(u, NEG_ATT * u);
      ps = fmaf(u, a[c], ps);
    }
    #pragma unroll
    for (int off = 16; off >= 1; off >>= 1) ps += __shfl_xor(ps, off);
  }
  float l = 0.f, acc[8];
  #pragma unroll
  for (int c = 0; c < 8; ++c) acc[c] = 0.f;
  int beg = rowptr[d], end = rowptr[d + 1];
  for (int j = beg; j < end; j += 4) {
    int j0 = j + half, j1 = j + 2 + half;
    bool v0 = j0 < end, v1 = j1 < end;
    int s0 = colsrc[v0 ? j0 : beg];
    int s1 = colsrc[v1 ? j1 : beg];
    uint4 r0 = *(const uint4*)(xlr + (size_t)s0 * S + c0);
    uint4 r1 = *(const uint4*)(xlr + (size_t)s1 * S + c0);
    float x0[8], x1[8];
    unpack8(r0, x0);
    unpack8(r1, x1);
    float p0 = 0.f, p1 = 0.f;
    #pragma unroll
    for (int c = 0; c < 8; ++c) {
      float u0 = x0[c] + xr_[c];
      float u1 = x1[c] + xr_[c];
      u0 = fmaxf(u0, NEG_ATT * u0);
      u1 = fmaxf(u1, NEG_ATT * u1);
      p0 = fmaf(u0, a[c], p0);
      p1 = fmaf(u1, a[c], p1);
    }
    #pragma unroll
    for (int off = 16; off >= 1; off >>= 1) {
      p0 += __shfl_xor(p0, off);
      p1 += __shfl_xor(p1, off);
    }
    float w0 = v0 ? __expf(p0 - ps) : 0.f;
    float w1 = v1 ? __expf(p1 - ps) : 0.f;
    l += w0 + w1;
    #pragma unroll
    for (int c = 0; c < 8; ++c) {
      acc[c] = fmaf(w0, x0[c], acc[c]);
      acc[c] = fmaf(w1, x1[c], acc[c]);
    }
  }
  l += __shfl_xor(l, 32);
  float inv = 1.f / l;
  float4 b0 = *(const float4*)(bias + c0);
  float4 b1 = *(const float4*)(bias + c0 + 4);
  float bb[8] = {b0.x, b0.y, b0.z, b0.w, b1.x, b1.y, b1.z, b1.w};
  float4 h0 = *(const float4*)(h + (size_t)d * 256 + c0);
  float4 h1v = *(const float4*)(h + (size_t)d * 256 + c0 + 4);
  float hh[8] = {h0.x, h0.y, h0.z, h0.w, h1v.x, h1v.y, h1v.z, h1v.w};
  float4 w0v = *(const float4*)(Wout + c0);
  float4 w1v = *(const float4*)(Wout + c0 + 4);
  float ww[8] = {w0v.x, w0v.y, w0v.z, w0v.w, w1v.x, w1v.y, w1v.z, w1v.w};
  float v = 0.f;
  #pragma unroll
  for (int c = 0; c < 8; ++c) {
    float s = acc[c] + __shfl_xor(acc[c], 32);
    float h3c = s * inv + bb[c];
    v = fmaf(lrelu(h3c, NEG) + hh[c], ww[c], v);
  }
  #pragma unroll
  for (int off = 16; off >= 1; off >>= 1) v += __shfl_xor(v, off);
  if (ln == 0) out[d] = v + bout[0];
}

extern "C" void kernel_launch(void* const* d_in, const int* in_sizes, int n_in,
                              void* d_out, int out_size, void* d_ws, size_t ws_size,
                              hipStream_t stream) {
  const float* x    = (const float*)d_in[0];
  const int*   src  = (const int*)d_in[1];
  const int*   dst  = (const int*)d_in[2];
  const float* W_in = (const float*)d_in[3];
  const float* b_in = (const float*)d_in[4];
  const float* Wl1 = (const float*)d_in[5];  const float* bl1 = (const float*)d_in[6];
  const float* Wr1 = (const float*)d_in[7];  const float* br1 = (const float*)d_in[8];
  const float* att1 = (const float*)d_in[9]; const float* bias1 = (const float*)d_in[10];
  const float* Wl2 = (const float*)d_in[11]; const float* bl2 = (const float*)d_in[12];
  const float* Wr2 = (const float*)d_in[13]; const float* br2 = (const float*)d_in[14];
  const float* att2 = (const float*)d_in[15]; const float* bias2 = (const float*)d_in[16];
  const float* Wl3 = (const float*)d_in[17]; const float* bl3 = (const float*)d_in[18];
  const float* Wr3 = (const float*)d_in[19]; const float* br3 = (const float*)d_in[20];
  const float* att3 = (const float*)d_in[21]; const float* bias3 = (const float*)d_in[22];
  const float* W_out = (const float*)d_in[23]; const float* b_out = (const float*)d_in[24];

  const int N = in_sizes[0] / 64;
  const int E = in_sizes[1];
  const int NP = ((N + 127) / 128) * 128;   // padded rows for GEMM-A buffers
  float* out = (float*)d_out;

  // ---- workspace layout. Total ~206 MB ----
  char* p = (char*)d_ws;
  float* h   = (float*)p;            p += (size_t)N * 256 * 4;   // fp32 residual
  unsigned short* xbf  = (unsigned short*)p; p += (size_t)NP * 64 * 2;
  unsigned short* hbf  = (unsigned short*)p; p += (size_t)NP * 256 * 2;
  unsigned short* h1bf = (unsigned short*)p; p += (size_t)NP * 1024 * 2;
  unsigned short* h2bf = (unsigned short*)p; p += (size_t)NP * 1024 * 2;
  unsigned short* xlr  = (unsigned short*)p; p += (size_t)N * 2048 * 2;
  unsigned short* WtIn  = (unsigned short*)p; p += (size_t)256 * 64 * 2;
  unsigned short* WtLR1 = (unsigned short*)p; p += (size_t)2048 * 256 * 2;
  unsigned short* WtLR2 = (unsigned short*)p; p += (size_t)2048 * 1024 * 2;
  unsigned short* WtLR3 = (unsigned short*)p; p += (size_t)512 * 1024 * 2;
  float* bLR1 = (float*)p;           p += (size_t)2048 * 4;
  float* bLR2 = (float*)p;           p += (size_t)2048 * 4;
  float* bLR3 = (float*)p;           p += (size_t)512 * 4;
  int* cnt    = (int*)p;             p += (size_t)N * 4;
  int* cursor = (int*)p;             p += (size_t)N * 4;
  int* rowptr = (int*)p;             p += (size_t)(N + 1) * 4;
  int* colsrc = (int*)p;

  const int tot = E + N;
  dim3 blk(256);

  // CSR build (by dst, self loops appended)
  zero_int_kernel<<<(N + 255) / 256, blk, 0, stream>>>(cnt, N);
  hist_kernel<<<(tot + 255) / 256, blk, 0, stream>>>(dst, cnt, E, N);
  scan_kernel<<<1, 1024, 0, stream>>>(cnt, rowptr, cursor, N);
  fill_kernel<<<(tot + 255) / 256, blk, 0, stream>>>(src, dst, cursor, colsrc, E, N);

  // fused prep: all transposes + f2b(x) + bias concat in one dispatch
  int nbf2b = (N * 64 + 255) / 256;
  prep_all<<<3106 + nbf2b, blk, 0, stream>>>(
      W_in, Wl1, Wr1, Wl2, Wr2, Wl3, Wr3,
      WtIn, WtLR1, WtLR1 + (size_t)1024 * 256,
      WtLR2, WtLR2 + (size_t)1024 * 1024,
      WtLR3, WtLR3 + (size_t)256 * 1024,
      x, xbf, N * 64,
      bl1, br1, bl2, br2, bl3, br3, bLR1, bLR2, bLR3);

  int gy = NP / 128;
  int gagg4 = N;
  int gagg1 = (N + 3) / 4;

  // h = leaky(x @ W_in + b_in): fp32 h + bf16 hbf   [K=64]
  gemm_mfma<<<dim3(2, gy), blk, 0, stream>>>(xbf, WtIn, b_in, h, hbf, N, 64, 256, 256, 1);

  // layer 1: K=256, fused L|R -> xlr [N,2048]
  gemm_mfma<<<dim3(16, gy), blk, 0, stream>>>(hbf, WtLR1, bLR1, nullptr, xlr, N, 256, 0, 2048, 0);
  gat_agg_h4<<<gagg4, blk, 0, stream>>>(xlr, rowptr, colsrc, att1, bias1, h1bf, N);

  // layer 2: K=1024, fused L|R -> xlr [N,2048]
  gemm_mfma<<<dim3(16, gy), blk, 0, stream>>>(h1bf, WtLR2, bLR2, nullptr, xlr, N, 1024, 0, 2048, 0);
  gat_agg_h4<<<gagg4, blk, 0, stream>>>(xlr, rowptr, colsrc, att2, bias2, h2bf, N);

  // layer 3: K=1024, fused L|R -> xlr [N,512]; agg + residual + logits fused
  gemm_mfma<<<dim3(4, gy), blk, 0, stream>>>(h2bf, WtLR3, bLR3, nullptr, xlr, N, 1024, 0, 512, 0);
  gat_agg_h1_final<<<gagg1, blk, 0, stream>>>(xlr, rowptr, colsrc, att3, bias3,
                                              h, W_out, b_out, out, N);
}

// Round 9
// 703.857 us; speedup vs baseline: 1.1416x; 1.0198x over previous
//
#include <hip/hip_runtime.h>
#include <math.h>

#define NEG_ATT 0.2f
#define NEG 0.01f

typedef __attribute__((ext_vector_type(8))) short short8;
typedef __attribute__((ext_vector_type(4))) float f32x4;

static __device__ __forceinline__ float lrelu(float x, float s) { return x > 0.f ? x : s * x; }
static __device__ __forceinline__ unsigned short f2b(float f) {
  union { float f; unsigned int i; } v; v.f = f;
  unsigned int r = (v.i + 0x7fffu + ((v.i >> 16) & 1u)) >> 16;
  return (unsigned short)r;
}
static __device__ __forceinline__ void unpack8(uint4 r, float* x) {
  union { unsigned int u; float f; } t;
  t.u = r.x << 16;          x[0] = t.f;
  t.u = r.x & 0xffff0000u;  x[1] = t.f;
  t.u = r.y << 16;          x[2] = t.f;
  t.u = r.y & 0xffff0000u;  x[3] = t.f;
  t.u = r.z << 16;          x[4] = t.f;
  t.u = r.z & 0xffff0000u;  x[5] = t.f;
  t.u = r.w << 16;          x[6] = t.f;
  t.u = r.w & 0xffff0000u;  x[7] = t.f;
}

// ---------------- CSR build ----------------
__global__ void zero_int_kernel(int* __restrict__ p, int n) {
  int i = blockIdx.x * blockDim.x + threadIdx.x;
  if (i < n) p[i] = 0;
}

__global__ void hist_kernel(const int* __restrict__ dst, int* __restrict__ cnt, int E, int N) {
  int i = blockIdx.x * blockDim.x + threadIdx.x;
  int tot = E + N;
  if (i >= tot) return;
  int d = (i < E) ? dst[i] : (i - E);
  atomicAdd(&cnt[d], 1);
}

// single-block exclusive scan, shfl-based
__global__ void scan_kernel(const int* __restrict__ cnt, int* __restrict__ rowptr,
                            int* __restrict__ cursor, int n) {
  __shared__ int wsum[16];
  __shared__ int carry_s;
  int t = threadIdx.x;           // 1024 threads
  int lane = t & 63, wv = t >> 6;
  if (t == 0) carry_s = 0;
  __syncthreads();
  for (int base = 0; base < n; base += 1024) {
    int i = base + t;
    int orig = (i < n) ? cnt[i] : 0;
    int v = orig;
    #pragma unroll
    for (int off = 1; off < 64; off <<= 1) {
      int u = __shfl_up(v, off);
      if (lane >= off) v += u;
    }
    if (lane == 63) wsum[wv] = v;
    __syncthreads();
    if (t < 16) {
      int s = wsum[t];
      #pragma unroll
      for (int off = 1; off < 16; off <<= 1) {
        int u = __shfl_up(s, off);
        if (t >= off) s += u;
      }
      wsum[t] = s;
    }
    __syncthreads();
    int waveoff = (wv > 0) ? wsum[wv - 1] : 0;
    int carry = carry_s;
    int excl = carry + waveoff + v - orig;
    if (i < n) { rowptr[i] = excl; cursor[i] = excl; }
    __syncthreads();
    if (t == 0) carry_s = carry + wsum[15];
    __syncthreads();
  }
  if (t == 0) rowptr[n] = carry_s;
}

__global__ void fill_kernel(const int* __restrict__ src, const int* __restrict__ dst,
                            int* __restrict__ cursor, int* __restrict__ colsrc, int E, int N) {
  int i = blockIdx.x * blockDim.x + threadIdx.x;
  int tot = E + N;
  if (i >= tot) return;
  int d, s;
  if (i < E) { d = dst[i]; s = src[i]; } else { d = i - E; s = i - E; }
  int pos = atomicAdd(&cursor[d], 1);
  colsrc[pos] = s;
}

// ---------------- fused prep: 7 weight transposes + f2b(x) + bias concat ----------------
static __device__ __forceinline__ void do_transpose(
    const float* __restrict__ W, unsigned short* __restrict__ Wt,
    int K, int Ncol, int lbid, float (*t)[33]) {
  int nxb = Ncol >> 5;
  int bx = lbid % nxb, by = lbid / nxb;
  int n0 = bx * 32, k0 = by * 32;
  int tx = threadIdx.x & 31, ty = threadIdx.x >> 5;  // ty 0..7
  #pragma unroll
  for (int i = 0; i < 4; ++i)
    t[ty + i * 8][tx] = W[(size_t)(k0 + ty + i * 8) * Ncol + n0 + tx];
  __syncthreads();
  #pragma unroll
  for (int i = 0; i < 4; ++i)
    Wt[(size_t)(n0 + ty + i * 8) * K + k0 + tx] = f2b(t[tx][ty + i * 8]);
}

// block ranges: [0,16) t0 | [16,272) t1 | [272,528) t2 | [528,1552) t3 |
// [1552,2576) t4 | [2576,2832) t5 | [2832,3088) t6 | [3088,3106) bias | [3106,..) f2b(x)
__global__ __launch_bounds__(256) void prep_all(
    const float* __restrict__ W_in,
    const float* __restrict__ Wl1, const float* __restrict__ Wr1,
    const float* __restrict__ Wl2, const float* __restrict__ Wr2,
    const float* __restrict__ Wl3, const float* __restrict__ Wr3,
    unsigned short* __restrict__ WtIn,
    unsigned short* __restrict__ WtL1, unsigned short* __restrict__ WtR1,
    unsigned short* __restrict__ WtL2, unsigned short* __restrict__ WtR2,
    unsigned short* __restrict__ WtL3, unsigned short* __restrict__ WtR3,
    const float* __restrict__ x, unsigned short* __restrict__ xbf, int nx_elems,
    const float* __restrict__ bl1, const float* __restrict__ br1,
    const float* __restrict__ bl2, const float* __restrict__ br2,
    const float* __restrict__ bl3, const float* __restrict__ br3,
    float* __restrict__ bLR1, float* __restrict__ bLR2, float* __restrict__ bLR3) {
  __shared__ float t[32][33];
  int bid = blockIdx.x;
  if (bid < 16)        { do_transpose(W_in, WtIn, 64, 256, bid, t); return; }
  if (bid < 272)       { do_transpose(Wl1, WtL1, 256, 1024, bid - 16, t); return; }
  if (bid < 528)       { do_transpose(Wr1, WtR1, 256, 1024, bid - 272, t); return; }
  if (bid < 1552)      { do_transpose(Wl2, WtL2, 1024, 1024, bid - 528, t); return; }
  if (bid < 2576)      { do_transpose(Wr2, WtR2, 1024, 1024, bid - 1552, t); return; }
  if (bid < 2832)      { do_transpose(Wl3, WtL3, 1024, 256, bid - 2576, t); return; }
  if (bid < 3088)      { do_transpose(Wr3, WtR3, 1024, 256, bid - 2832, t); return; }
  if (bid < 3106) {
    int i = (bid - 3088) * 256 + threadIdx.x;   // 0..4607
    if (i < 1024)      bLR1[i] = bl1[i];
    else if (i < 2048) bLR1[i] = br1[i - 1024];
    else if (i < 3072) bLR2[i - 2048] = bl2[i - 2048];
    else if (i < 4096) bLR2[i - 2048] = br2[i - 3072];
    else if (i < 4352) bLR3[i - 4096] = bl3[i - 4096];
    else if (i < 4608) bLR3[i - 4096] = br3[i - 4352];
    return;
  }
  int i = (bid - 3106) * 256 + threadIdx.x;
  if (i < nx_elems) xbf[i] = f2b(x[i]);
}

// ---------------- bf16 MFMA GEMM: BK=64, register prefetch, 8-chunk XOR swizzle ------
// A row-major [NP][K] bf16, NP = ceil(M/128)*128. Bt row-major [Ncol][K].
// 128x128 tile, 256 thr = 4 waves (2x2 of 64x64), BK=64 (2 MFMA sub-steps/barrier).
// LDS row = 64 shorts = 8 chunks of 8; logical chunk c (c = h*4+q) of row r lives at
// physical chunk c ^ f(r), f(r) = ((r&1)<<2)|((r>>1)&3). Staging ds_write_b128 and
// fragment ds_read_b128 phases each hit all 32 banks exactly once (0 conflicts).
// For frag reads f(r) collapses to ((l16&1)<<2)|((l16>>1)&3) — loop-invariant.
__global__ __launch_bounds__(256) void gemm_mfma(
    const unsigned short* __restrict__ A, const unsigned short* __restrict__ Bt,
    const float* __restrict__ bias, float* __restrict__ Cf, unsigned short* __restrict__ Cb,
    int M, int K, int ldcf, int ldcb, int act) {
  __shared__ __align__(16) unsigned short As[128 * 64];
  __shared__ __align__(16) unsigned short Bs[128 * 64];
  int tid = threadIdx.x;
  int wave = tid >> 6, lane = tid & 63;
  int wm = wave >> 1, wn = wave & 1;
  int quad = lane >> 4, l16 = lane & 15;
  int row0 = blockIdx.y * 128, col0 = blockIdx.x * 128;
  int r0 = tid >> 2, seg0 = tid & 3;
  int f0 = ((r0 & 1) << 2) | ((r0 >> 1) & 3);          // staging swizzle (r0 and r0+64 same)
  int wsl0 = r0 * 64 + ((seg0 ^ f0) * 8);              // logical c = seg0     (h=0)
  int wsl1 = r0 * 64 + (((seg0 | 4) ^ f0) * 8);        // logical c = seg0+4   (h=1)
  int wsl2 = wsl0 + 64 * 64;                           // row r0+64, h=0
  int wsl3 = wsl1 + 64 * 64;                           // row r0+64, h=1
  int flane = ((l16 & 1) << 2) | ((l16 >> 1) & 3);     // frag-read swizzle, loop-invariant

  const unsigned short* gA = A + (size_t)(row0 + r0) * K + seg0 * 8;
  const unsigned short* gB = Bt + (size_t)(col0 + r0) * K + seg0 * 8;
  const size_t rstep = (size_t)64 * K;

  f32x4 acc[4][4];
  #pragma unroll
  for (int i = 0; i < 4; ++i)
    #pragma unroll
    for (int j = 0; j < 4; ++j)
      acc[i][j] = (f32x4){0.f, 0.f, 0.f, 0.f};

  uint4 pa0 = *(const uint4*)(gA);
  uint4 pa1 = *(const uint4*)(gA + 32);
  uint4 pa2 = *(const uint4*)(gA + rstep);
  uint4 pa3 = *(const uint4*)(gA + rstep + 32);
  uint4 pb0 = *(const uint4*)(gB);
  uint4 pb1 = *(const uint4*)(gB + 32);
  uint4 pb2 = *(const uint4*)(gB + rstep);
  uint4 pb3 = *(const uint4*)(gB + rstep + 32);

  for (int k0 = 0; k0 < K; k0 += 64) {
    *(uint4*)&As[wsl0] = pa0;
    *(uint4*)&As[wsl1] = pa1;
    *(uint4*)&As[wsl2] = pa2;
    *(uint4*)&As[wsl3] = pa3;
    *(uint4*)&Bs[wsl0] = pb0;
    *(uint4*)&Bs[wsl1] = pb1;
    *(uint4*)&Bs[wsl2] = pb2;
    *(uint4*)&Bs[wsl3] = pb3;
    __syncthreads();
    int kn = k0 + 64;
    if (kn < K) {     // prefetch next slab while MFMA runs
      pa0 = *(const uint4*)(gA + kn);
      pa1 = *(const uint4*)(gA + kn + 32);
      pa2 = *(const uint4*)(gA + kn + rstep);
      pa3 = *(const uint4*)(gA + kn + rstep + 32);
      pb0 = *(const uint4*)(gB + kn);
      pb1 = *(const uint4*)(gB + kn + 32);
      pb2 = *(const uint4*)(gB + kn + rstep);
      pb3 = *(const uint4*)(gB + kn + rstep + 32);
    }
    #pragma unroll
    for (int h = 0; h < 2; ++h) {
      short8 afr[4], bfr[4];
      #pragma unroll
      for (int t = 0; t < 4; ++t) {
        int pcs = (((h << 2) | quad) ^ flane) * 8;
        afr[t] = *(const short8*)&As[(wm * 64 + t * 16 + l16) * 64 + pcs];
        bfr[t] = *(const short8*)&Bs[(wn * 64 + t * 16 + l16) * 64 + pcs];
      }
      #pragma unroll
      for (int mt = 0; mt < 4; ++mt)
        #pragma unroll
        for (int nt = 0; nt < 4; ++nt)
          acc[mt][nt] = __builtin_amdgcn_mfma_f32_16x16x32_bf16(afr[mt], bfr[nt], acc[mt][nt], 0, 0, 0);
    }
    __syncthreads();
  }

  #pragma unroll
  for (int mt = 0; mt < 4; ++mt) {
    #pragma unroll
    for (int r = 0; r < 4; ++r) {
      int row = row0 + wm * 64 + mt * 16 + quad * 4 + r;
      if (row >= M) continue;
      #pragma unroll
      for (int nt = 0; nt < 4; ++nt) {
        int col = col0 + wn * 64 + nt * 16 + l16;
        float v = acc[mt][nt][r] + bias[col];
        if (act == 1) v = lrelu(v, NEG);
        if (Cf) Cf[(size_t)row * ldcf + col] = v;
        if (Cb) Cb[(size_t)row * ldcb + col] = f2b(v);
      }
    }
  }
}

// ---------------- GATv2 aggregation, 4 heads: self-centered softmax, 4 edges/iter ----
__global__ __launch_bounds__(256) void gat_agg_h4(
    const unsigned short* __restrict__ xlr,
    const int* __restrict__ rowptr, const int* __restrict__ colsrc,
    const float* __restrict__ att, const float* __restrict__ bias,
    unsigned short* __restrict__ outb, int n) {
  const int S = 2048, XROFF = 1024;
  int d = blockIdx.x;
  if (d >= n) return;
  int hd = threadIdx.x >> 6, ln = threadIdx.x & 63;
  int half = ln >> 5, l32 = ln & 31;
  int c0 = l32 * 8;
  float a[8], xr_[8];
  {
    float4 t0 = *(const float4*)(att + hd * 256 + c0);
    float4 t1 = *(const float4*)(att + hd * 256 + c0 + 4);
    a[0]=t0.x; a[1]=t0.y; a[2]=t0.z; a[3]=t0.w;
    a[4]=t1.x; a[5]=t1.y; a[6]=t1.z; a[7]=t1.w;
    uint4 r = *(const uint4*)(xlr + (size_t)d * S + XROFF + hd * 256 + c0);
    unpack8(r, xr_);
  }
  // self-loop score as softmax center
  float ps = 0.f;
  {
    uint4 r = *(const uint4*)(xlr + (size_t)d * S + hd * 256 + c0);
    float xs[8];
    unpack8(r, xs);
    #pragma unroll
    for (int c = 0; c < 8; ++c) {
      float u = xs[c] + xr_[c];
      u = fmaxf(u, NEG_ATT * u);
      ps = fmaf(u, a[c], ps);
    }
    #pragma unroll
    for (int off = 16; off >= 1; off >>= 1) ps += __shfl_xor(ps, off);
  }
  float l = 0.f, acc[8];
  #pragma unroll
  for (int c = 0; c < 8; ++c) acc[c] = 0.f;
  int beg = rowptr[d], end = rowptr[d + 1];
  for (int j = beg; j < end; j += 4) {
    int j0 = j + half, j1 = j + 2 + half;
    bool v0 = j0 < end, v1 = j1 < end;
    int s0 = colsrc[v0 ? j0 : beg];
    int s1 = colsrc[v1 ? j1 : beg];
    uint4 r0 = *(const uint4*)(xlr + (size_t)s0 * S + hd * 256 + c0);
    uint4 r1 = *(const uint4*)(xlr + (size_t)s1 * S + hd * 256 + c0);
    float x0[8], x1[8];
    unpack8(r0, x0);
    unpack8(r1, x1);
    float p0 = 0.f, p1 = 0.f;
    #pragma unroll
    for (int c = 0; c < 8; ++c) {
      float u0 = x0[c] + xr_[c];
      float u1 = x1[c] + xr_[c];
      u0 = fmaxf(u0, NEG_ATT * u0);
      u1 = fmaxf(u1, NEG_ATT * u1);
      p0 = fmaf(u0, a[c], p0);
      p1 = fmaf(u1, a[c], p1);
    }
    #pragma unroll
    for (int off = 16; off >= 1; off >>= 1) {
      p0 += __shfl_xor(p0, off);
      p1 += __shfl_xor(p1, off);
    }
    float w0 = v0 ? __expf(p0 - ps) : 0.f;
    float w1 = v1 ? __expf(p1 - ps) : 0.f;
    l += w0 + w1;
    #pragma unroll
    for (int c = 0; c < 8; ++c) {
      acc[c] = fmaf(w0, x0[c], acc[c]);
      acc[c] = fmaf(w1, x1[c], acc[c]);
    }
  }
  // merge halves (shared center -> plain adds)
  l += __shfl_xor(l, 32);
  float inv = 1.f / l;
  float4 b0 = *(const float4*)(bias + hd * 256 + c0);
  float4 b1 = *(const float4*)(bias + hd * 256 + c0 + 4);
  float bb[8] = {b0.x, b0.y, b0.z, b0.w, b1.x, b1.y, b1.z, b1.w};
  unsigned int ou[4];
  #pragma unroll
  for (int c = 0; c < 8; ++c) {
    float s = acc[c] + __shfl_xor(acc[c], 32);
    float v = s * inv + bb[c];
    v = v > 0.f ? v : expm1f(v);     // ELU
    unsigned int bv = (unsigned int)f2b(v);
    if (c & 1) ou[c >> 1] |= bv << 16; else ou[c >> 1] = bv;
  }
  if (half == 0) {
    uint4 o = make_uint4(ou[0], ou[1], ou[2], ou[3]);
    *(uint4*)(outb + (size_t)d * 1024 + hd * 256 + c0) = o;
  }
}

// ---------------- fused layer-3 agg + final logits (self-centered, 4 edges/iter) ----
__global__ __launch_bounds__(256) void gat_agg_h1_final(
    const unsigned short* __restrict__ xlr,
    const int* __restrict__ rowptr, const int* __restrict__ colsrc,
    const float* __restrict__ att, const float* __restrict__ bias,
    const float* __restrict__ h, const float* __restrict__ Wout,
    const float* __restrict__ bout, float* __restrict__ out, int n) {
  const int S = 512, XROFF = 256;
  int wv = threadIdx.x >> 6, ln = threadIdx.x & 63;
  int d = blockIdx.x * 4 + wv;
  if (d >= n) return;
  int half = ln >> 5, l32 = ln & 31;
  int c0 = l32 * 8;
  float a[8], xr_[8];
  {
    float4 t0 = *(const float4*)(att + c0);
    float4 t1 = *(const float4*)(att + c0 + 4);
    a[0]=t0.x; a[1]=t0.y; a[2]=t0.z; a[3]=t0.w;
    a[4]=t1.x; a[5]=t1.y; a[6]=t1.z; a[7]=t1.w;
    uint4 r = *(const uint4*)(xlr + (size_t)d * S + XROFF + c0);
    unpack8(r, xr_);
  }
  float ps = 0.f;
  {
    uint4 r = *(const uint4*)(xlr + (size_t)d * S + c0);
    float xs[8];
    unpack8(r, xs);
    #pragma unroll
    for (int c = 0; c < 8; ++c) {
      float u = xs[c] + xr_[c];
      u = fmaxf(u, NEG_ATT * u);
      ps = fmaf(u, a[c], ps);
    }
    #pragma unroll
    for (int off = 16; off >= 1; off >>= 1) ps += __shfl_xor(ps, off);
  }
  float l = 0.f, acc[8];
  #pragma unroll
  for (int c = 0; c < 8; ++c) acc[c] = 0.f;
  int beg = rowptr[d], end = rowptr[d + 1];
  for (int j = beg; j < end; j += 4) {
    int j0 = j + half, j1 = j + 2 + half;
    bool v0 = j0 < end, v1 = j1 < end;
    int s0 = colsrc[v0 ? j0 : beg];
    int s1 = colsrc[v1 ? j1 : beg];
    uint4 r0 = *(const uint4*)(xlr + (size_t)s0 * S + c0);
    uint4 r1 = *(const uint4*)(xlr + (size_t)s1 * S + c0);
    float x0[8], x1[8];
    unpack8(r0, x0);
    unpack8(r1, x1);
    float p0 = 0.f, p1 = 0.f;
    #pragma unroll
    for (int c = 0; c < 8; ++c) {
      float u0 = x0[c] + xr_[c];
      float u1 = x1[c] + xr_[c];
      u0 = fmaxf(u0, NEG_ATT * u0);
      u1 = fmaxf(u1, NEG_ATT * u1);
      p0 = fmaf(u0, a[c], p0);
      p1 = fmaf(u1, a[c], p1);
    }
    #pragma unroll
    for (int off = 16; off >= 1; off >>= 1) {
      p0 += __shfl_xor(p0, off);
      p1 += __shfl_xor(p1, off);
    }
    float w0 = v0 ? __expf(p0 - ps) : 0.f;
    float w1 = v1 ? __expf(p1 - ps) : 0.f;
    l += w0 + w1;
    #pragma unroll
    for (int c = 0; c < 8; ++c) {
      acc[c] = fmaf(w0, x0[c], acc[c]);
      acc[c] = fmaf(w1, x1[c], acc[c]);
    }
  }
  l += __shfl_xor(l, 32);
  float inv = 1.f / l;
  float4 b0 = *(const float4*)(bias + c0);
  float4 b1 = *(const float4*)(bias + c0 + 4);
  float bb[8] = {b0.x, b0.y, b0.z, b0.w, b1.x, b1.y, b1.z, b1.w};
  float4 h0 = *(const float4*)(h + (size_t)d * 256 + c0);
  float4 h1v = *(const float4*)(h + (size_t)d * 256 + c0 + 4);
  float hh[8] = {h0.x, h0.y, h0.z, h0.w, h1v.x, h1v.y, h1v.z, h1v.w};
  float4 w0v = *(const float4*)(Wout + c0);
  float4 w1v = *(const float4*)(Wout + c0 + 4);
  float ww[8] = {w0v.x, w0v.y, w0v.z, w0v.w, w1v.x, w1v.y, w1v.z, w1v.w};
  float v = 0.f;
  #pragma unroll
  for (int c = 0; c < 8; ++c) {
    float s = acc[c] + __shfl_xor(acc[c], 32);
    float h3c = s * inv + bb[c];
    v = fmaf(lrelu(h3c, NEG) + hh[c], ww[c], v);
  }
  #pragma unroll
  for (int off = 16; off >= 1; off >>= 1) v += __shfl_xor(v, off);
  if (ln == 0) out[d] = v + bout[0];
}

extern "C" void kernel_launch(void* const* d_in, const int* in_sizes, int n_in,
                              void* d_out, int out_size, void* d_ws, size_t ws_size,
                              hipStream_t stream) {
  const float* x    = (const float*)d_in[0];
  const int*   src  = (const int*)d_in[1];
  const int*   dst  = (const int*)d_in[2];
  const float* W_in = (const float*)d_in[3];
  const float* b_in = (const float*)d_in[4];
  const float* Wl1 = (const float*)d_in[5];  const float* bl1 = (const float*)d_in[6];
  const float* Wr1 = (const float*)d_in[7];  const float* br1 = (const float*)d_in[8];
  const float* att1 = (const float*)d_in[9]; const float* bias1 = (const float*)d_in[10];
  const float* Wl2 = (const float*)d_in[11]; const float* bl2 = (const float*)d_in[12];
  const float* Wr2 = (const float*)d_in[13]; const float* br2 = (const float*)d_in[14];
  const float* att2 = (const float*)d_in[15]; const float* bias2 = (const float*)d_in[16];
  const float* Wl3 = (const float*)d_in[17]; const float* bl3 = (const float*)d_in[18];
  const float* Wr3 = (const float*)d_in[19]; const float* br3 = (const float*)d_in[20];
  const float* att3 = (const float*)d_in[21]; const float* bias3 = (const float*)d_in[22];
  const float* W_out = (const float*)d_in[23]; const float* b_out = (const float*)d_in[24];

  const int N = in_sizes[0] / 64;
  const int E = in_sizes[1];
  const int NP = ((N + 127) / 128) * 128;   // padded rows for GEMM-A buffers
  float* out = (float*)d_out;

  // ---- workspace layout. Total ~206 MB ----
  char* p = (char*)d_ws;
  float* h   = (float*)p;            p += (size_t)N * 256 * 4;   // fp32 residual
  unsigned short* xbf  = (unsigned short*)p; p += (size_t)NP * 64 * 2;
  unsigned short* hbf  = (unsigned short*)p; p += (size_t)NP * 256 * 2;
  unsigned short* h1bf = (unsigned short*)p; p += (size_t)NP * 1024 * 2;
  unsigned short* h2bf = (unsigned short*)p; p += (size_t)NP * 1024 * 2;
  unsigned short* xlr  = (unsigned short*)p; p += (size_t)N * 2048 * 2;
  unsigned short* WtIn  = (unsigned short*)p; p += (size_t)256 * 64 * 2;
  unsigned short* WtLR1 = (unsigned short*)p; p += (size_t)2048 * 256 * 2;
  unsigned short* WtLR2 = (unsigned short*)p; p += (size_t)2048 * 1024 * 2;
  unsigned short* WtLR3 = (unsigned short*)p; p += (size_t)512 * 1024 * 2;
  float* bLR1 = (float*)p;           p += (size_t)2048 * 4;
  float* bLR2 = (float*)p;           p += (size_t)2048 * 4;
  float* bLR3 = (float*)p;           p += (size_t)512 * 4;
  int* cnt    = (int*)p;             p += (size_t)N * 4;
  int* cursor = (int*)p;             p += (size_t)N * 4;
  int* rowptr = (int*)p;             p += (size_t)(N + 1) * 4;
  int* colsrc = (int*)p;

  const int tot = E + N;
  dim3 blk(256);

  // CSR build (by dst, self loops appended)
  zero_int_kernel<<<(N + 255) / 256, blk, 0, stream>>>(cnt, N);
  hist_kernel<<<(tot + 255) / 256, blk, 0, stream>>>(dst, cnt, E, N);
  scan_kernel<<<1, 1024, 0, stream>>>(cnt, rowptr, cursor, N);
  fill_kernel<<<(tot + 255) / 256, blk, 0, stream>>>(src, dst, cursor, colsrc, E, N);

  // fused prep: all transposes + f2b(x) + bias concat in one dispatch
  int nbf2b = (N * 64 + 255) / 256;
  prep_all<<<3106 + nbf2b, blk, 0, stream>>>(
      W_in, Wl1, Wr1, Wl2, Wr2, Wl3, Wr3,
      WtIn, WtLR1, WtLR1 + (size_t)1024 * 256,
      WtLR2, WtLR2 + (size_t)1024 * 1024,
      WtLR3, WtLR3 + (size_t)256 * 1024,
      x, xbf, N * 64,
      bl1, br1, bl2, br2, bl3, br3, bLR1, bLR2, bLR3);

  int gy = NP / 128;
  int gagg4 = N;
  int gagg1 = (N + 3) / 4;

  // h = leaky(x @ W_in + b_in): fp32 h + bf16 hbf   [K=64]
  gemm_mfma<<<dim3(2, gy), blk, 0, stream>>>(xbf, WtIn, b_in, h, hbf, N, 64, 256, 256, 1);

  // layer 1: K=256, fused L|R -> xlr [N,2048]
  gemm_mfma<<<dim3(16, gy), blk, 0, stream>>>(hbf, WtLR1, bLR1, nullptr, xlr, N, 256, 0, 2048, 0);
  gat_agg_h4<<<gagg4, blk, 0, stream>>>(xlr, rowptr, colsrc, att1, bias1, h1bf, N);

  // layer 2: K=1024, fused L|R -> xlr [N,2048]
  gemm_mfma<<<dim3(16, gy), blk, 0, stream>>>(h1bf, WtLR2, bLR2, nullptr, xlr, N, 1024, 0, 2048, 0);
  gat_agg_h4<<<gagg4, blk, 0, stream>>>(xlr, rowptr, colsrc, att2, bias2, h2bf, N);

  // layer 3: K=1024, fused L|R -> xlr [N,512]; agg + residual + logits fused
  gemm_mfma<<<dim3(4, gy), blk, 0, stream>>>(h2bf, WtLR3, bLR3, nullptr, xlr, N, 1024, 0, 512, 0);
  gat_agg_h1_final<<<gagg1, blk, 0, stream>>>(xlr, rowptr, colsrc, att3, bias3,
                                              h, W_out, b_out, out, N);
}